// Round 7
// baseline (417.144 us; speedup 1.0000x reference)
//
#include <hip/hip_runtime.h>

#define NH 4
#define N_RES 1000
#define E_RES 4000
#define N_ATOM 14000
#define E_ATOM 784000
#define MAXS 128   // src-slab slots/atom (Poisson λ=56, 128 is ~9.6σ)
#define NBRE 32    // persistent blocks for k_re2

#define BUILD_BLKS ((E_ATOM + 255) / 256)       // 3063
#define PROJ_BLKS ((N_ATOM * 192 + 255) / 256)  // 10500
#define RLB_BLKS (E_RES / 4)                    // 1000

typedef float f32x4 __attribute__((ext_vector_type(4)));

__device__ __forceinline__ unsigned enc_f(float f) {
  unsigned u = __float_as_uint(f);
  return (u & 0x80000000u) ? ~u : (u | 0x80000000u);
}
__device__ __forceinline__ float dec_f(unsigned e) {
  unsigned u = (e & 0x80000000u) ? (e & 0x7FFFFFFFu) : ~e;
  return __uint_as_float(u);
}

// ---- fused: slab build (src side only) + Q/K/V proj + res_level_bias ------
__global__ __launch_bounds__(256) void kA(
    const int* __restrict__ cei, const int* __restrict__ aer,
    int* __restrict__ cnt_src, unsigned* __restrict__ pay,
    const float* __restrict__ af, const float* __restrict__ wq,
    const float* __restrict__ bq, const float* __restrict__ wkv,
    const float* __restrict__ bkv, float* __restrict__ Qa,
    float* __restrict__ Ka, float* __restrict__ Va,
    const float* __restrict__ ref_, const float* __restrict__ nf,
    const int* __restrict__ rei, const float* __restrict__ w1,
    const float* __restrict__ b1, const float* __restrict__ w2,
    const float* __restrict__ b2, float* __restrict__ rlb) {
  int b = blockIdx.x;
  if (b < BUILD_BLKS) {
    int e = b * 256 + threadIdx.x;
    if (e < E_ATOM) {
      int src = cei[E_ATOM + e];
      int dst = cei[e];
      int re = aer[e];
      int slot = atomicAdd(&cnt_src[src], 1);
      if (slot >= MAXS) slot = MAXS - 1;  // statistically unreachable
      pay[(size_t)src * MAXS + slot] = (unsigned)dst | ((unsigned)re << 16);
    }
  } else if (b < BUILD_BLKS + PROJ_BLKS) {
    int tid = (b - BUILD_BLKS) * 256 + threadIdx.x;
    if (tid < N_ATOM * 192) {
      int a = tid / 192, j = tid % 192;
      const float* row = af + a * 16;
      if (j < 64) {
        float acc = bq[j];
#pragma unroll
        for (int i = 0; i < 16; ++i) acc += row[i] * wq[i * 64 + j];
        Qa[a * 64 + j] = acc;
      } else if (j < 128) {
        int jj = j - 64;
        int col = ((jj >> 4) << 5) + (jj & 15);  // head h, k half
        float acc = bkv[col];
#pragma unroll
        for (int i = 0; i < 16; ++i) acc += row[i] * wkv[i * 128 + col];
        Ka[a * 64 + jj] = acc;
      } else {
        int jj = j - 128;
        int col = ((jj >> 4) << 5) + 16 + (jj & 15);  // head h, v half
        float acc = bkv[col];
#pragma unroll
        for (int i = 0; i < 16; ++i) acc += row[i] * wkv[i * 128 + col];
        Va[a * 64 + jj] = acc;
      }
    }
  } else {
    __shared__ float hid[4][16];
    int sub = threadIdx.x >> 6, l = threadIdx.x & 63;
    int r = (b - BUILD_BLKS - PROJ_BLKS) * 4 + sub;
    int r0 = rei[r], r1 = rei[E_RES + r];
    int j = l >> 2, pq = l & 3;
    float acc = 0.f;
    for (int i = pq; i < 320; i += 4) {
      float cc;
      if (i < 64) cc = ref_[r * 64 + i];
      else if (i < 192) cc = nf[r0 * 128 + (i - 64)];
      else cc = nf[r1 * 128 + (i - 192)];
      acc += cc * w1[i * 16 + j];
    }
    acc += __shfl_xor(acc, 1);
    acc += __shfl_xor(acc, 2);
    if (pq == 0) hid[sub][j] = fmaxf(acc + b1[j], 0.f);
    __syncthreads();
    if (l < 4) {
      float o = b2[l];
#pragma unroll
      for (int jj = 0; jj < 16; ++jj) o += hid[sub][jj] * w2[jj * 4 + l];
      rlb[r * 4 + l] = o;
    }
  }
}

// ---- per-edge R over slab slots (2 atoms per 256-block) -------------------
__global__ __launch_bounds__(256) void k_edgeR(
    const int* __restrict__ cnt_src, const unsigned* __restrict__ pay,
    const float* __restrict__ coords, const float* __restrict__ Qa,
    const float* __restrict__ Ka, const float* __restrict__ rlb,
    const float* __restrict__ rw1, const float* __restrict__ rb1,
    const float* __restrict__ rw2, const float* __restrict__ rb2,
    const float* __restrict__ rw3, const float* __restrict__ rb3,
    float* __restrict__ R_slab) {
  __shared__ float sw1[256], sw2[256], sw3[64], sb1[16], sb2[16], sb3[4];
  int l = threadIdx.x;
  sw1[l] = rw1[l];
  sw2[l] = rw2[l];
  if (l < 64) sw3[l] = rw3[l];
  if (l < 16) { sb1[l] = rb1[l]; sb2[l] = rb2[l]; }
  if (l < 4) sb3[l] = rb3[l];
  __syncthreads();
  int a = blockIdx.x * 2 + (l >> 7);
  int s = l & 127;
  int n = cnt_src[a];
  if (n > MAXS) n = MAXS;
  if (s >= n) return;
  unsigned pr = pay[(size_t)a * MAXS + s];
  int dst = (int)(pr & 0xFFFFu);
  int re = (int)(pr >> 16);
  float vx = coords[dst * 3 + 0] - coords[a * 3 + 0] + 1e-8f;
  float vy = coords[dst * 3 + 1] - coords[a * 3 + 1] + 1e-8f;
  float vz = coords[dst * 3 + 2] - coords[a * 3 + 2] + 1e-8f;
  float d = sqrtf(vx * vx + vy * vy + vz * vz);
  float rb[16], h1[16], h2[16];
  const float step = 20.0f / 15.0f;
  const float inv_sigma = 1.0f / 1.25f;
#pragma unroll
  for (int jj = 0; jj < 16; ++jj) {
    float t = (d - jj * step) * inv_sigma;
    rb[jj] = __expf(-t * t);
  }
#pragma unroll
  for (int k = 0; k < 16; ++k) {
    float acc = sb1[k];
#pragma unroll
    for (int jj = 0; jj < 16; ++jj) acc += rb[jj] * sw1[jj * 16 + k];
    h1[k] = fmaxf(acc, 0.f);
  }
#pragma unroll
  for (int k = 0; k < 16; ++k) {
    float acc = sb2[k];
#pragma unroll
    for (int jj = 0; jj < 16; ++jj) acc += h1[jj] * sw2[jj * 16 + k];
    h2[k] = fmaxf(acc, 0.f);
  }
  const float4* qp = (const float4*)(Qa + (size_t)a * 64);
  const float4* kp = (const float4*)(Ka + (size_t)dst * 64);
  float4 rlb4 = *(const float4*)(rlb + re * 4);
  const float* rlbp = (const float*)&rlb4;
  f32x4 Rv;
#pragma unroll
  for (int h = 0; h < NH; ++h) {
    float adb = sb3[h];
#pragma unroll
    for (int jj = 0; jj < 16; ++jj) adb += h2[jj] * sw3[jj * 4 + h];
    float dot = 0.f;
#pragma unroll
    for (int v4 = 0; v4 < 4; ++v4) {
      float4 q4 = qp[h * 4 + v4];
      float4 k4 = kp[h * 4 + v4];
      dot += q4.x * k4.x + q4.y * k4.y + q4.z * k4.z + q4.w * k4.w;
    }
    Rv[h] = dot * 0.25f + rlbp[h] + adb;
  }
  __builtin_nontemporal_store(Rv,
                              (f32x4*)(R_slab + (size_t)(a * MAXS + s) * 4));
}

// ---- per-re sums via LDS-replicated accumulators (no global atomics) ------
// 32 persistent blocks; each scans its atoms' slab rows, accumulates into a
// private LDS copy of {cnt[4000]} then {br[4000][4]}, and writes the copy out.
__global__ __launch_bounds__(1024) void k_re2(
    const int* __restrict__ cnt_src, const unsigned* __restrict__ pay,
    const float* __restrict__ R_slab, int* __restrict__ cntg,
    float* __restrict__ br_g) {
  __shared__ __align__(16) unsigned char smraw[64000];
  int* scnt = (int*)smraw;
  float* sbr = (float*)smraw;
  int tid = threadIdx.x;
  int bid = blockIdx.x;
  int wv = tid >> 6, lane = tid & 63;
  int gw = bid * 16 + wv;  // global wave id, 512 waves total
  // stage 1: counts per re
  for (int j = tid; j < E_RES; j += 1024) scnt[j] = 0;
  __syncthreads();
  for (int a = gw; a < N_ATOM; a += NBRE * 16) {
    int n = cnt_src[a];
    if (n > MAXS) n = MAXS;
    size_t base = (size_t)a * MAXS;
    for (int i = lane; i < n; i += 64) {
      int re = (int)(pay[base + i] >> 16);
      atomicAdd(&scnt[re], 1);
    }
  }
  __syncthreads();
  for (int j = tid; j < E_RES; j += 1024) cntg[bid * E_RES + j] = scnt[j];
  __syncthreads();
  // stage 2: per-re, per-head R sums
  for (int j = tid; j < E_RES * 4; j += 1024) sbr[j] = 0.f;
  __syncthreads();
  for (int a = gw; a < N_ATOM; a += NBRE * 16) {
    int n = cnt_src[a];
    if (n > MAXS) n = MAXS;
    size_t base = (size_t)a * MAXS;
    for (int i = lane; i < n; i += 64) {
      int re = (int)(pay[base + i] >> 16);
      f32x4 r = *(const f32x4*)(R_slab + (base + i) * 4);
      atomicAdd(&sbr[re * 4 + 0], r[0]);
      atomicAdd(&sbr[re * 4 + 1], r[1]);
      atomicAdd(&sbr[re * 4 + 2], r[2]);
      atomicAdd(&sbr[re * 4 + 3], r[3]);
    }
  }
  __syncthreads();
  for (int j = tid; j < E_RES * 4; j += 1024)
    br_g[(size_t)bid * E_RES * 4 + j] = sbr[j];
}

// ---- reduce the 32 copies -> block_r (already divided by count) -----------
__global__ __launch_bounds__(256) void k_red(const float* __restrict__ br_g,
                                             const int* __restrict__ cntg,
                                             float* __restrict__ block_r) {
  int t = blockIdx.x * blockDim.x + threadIdx.x;
  if (t >= E_RES * 4) return;
  int r = t >> 2;
  float s = 0.f;
  int c = 0;
#pragma unroll
  for (int b = 0; b < NBRE; ++b) {
    s += br_g[(size_t)b * E_RES * 4 + t];
    c += cntg[b * E_RES + r];
  }
  block_r[t] = s / fmaxf((float)c, 1.0f);
}

// ---- residue softmax (max, denom, beta) fully in LDS, single block --------
__global__ __launch_bounds__(1024) void k_br23(
    const float* __restrict__ block_r, const int* __restrict__ rei,
    float* __restrict__ beta) {
  __shared__ unsigned resm[N_RES * 4];
  __shared__ float ress[N_RES * 4];
  int tid = threadIdx.x;
  for (int j = tid; j < N_RES * 4; j += 1024) { resm[j] = 0u; ress[j] = 0.f; }
  __syncthreads();
  float brv[4][4];
  int r1v[4];
  for (int k = 0; k < 4; ++k) {
    int r = tid + k * 1024;
    if (r < E_RES) {
      r1v[k] = rei[E_RES + r];
#pragma unroll
      for (int h = 0; h < 4; ++h) {
        brv[k][h] = block_r[r * 4 + h];
        atomicMax(&resm[r1v[k] * 4 + h], enc_f(brv[k][h]));
      }
    }
  }
  __syncthreads();
  for (int k = 0; k < 4; ++k) {
    int r = tid + k * 1024;
    if (r < E_RES) {
#pragma unroll
      for (int h = 0; h < 4; ++h)
        atomicAdd(&ress[r1v[k] * 4 + h],
                  __expf(brv[k][h] - dec_f(resm[r1v[k] * 4 + h])));
    }
  }
  __syncthreads();
  for (int k = 0; k < 4; ++k) {
    int r = tid + k * 1024;
    if (r < E_RES) {
#pragma unroll
      for (int h = 0; h < 4; ++h)
        beta[r * 4 + h] = __expf(brv[k][h] - dec_f(resm[r1v[k] * 4 + h])) /
                          (ress[r1v[k] * 4 + h] + 1e-16f);
    }
  }
}

// ---- per src atom: exact 2-pass softmax + weighted V ----------------------
__global__ __launch_bounds__(256) void k_src(
    const int* __restrict__ cnt_src, const unsigned* __restrict__ pay,
    const float* __restrict__ R_slab, const float* __restrict__ beta,
    const float* __restrict__ Va, float* __restrict__ au) {
  int wid = (blockIdx.x * blockDim.x + threadIdx.x) >> 6;
  int l = threadIdx.x & 63;
  if (wid >= N_ATOM) return;
  int n = cnt_src[wid];
  if (n > MAXS) n = MAXS;
  int h = l >> 4;
  size_t rbase = (size_t)wid * MAXS;
  float m0 = -3.0e38f, m1 = -3.0e38f, m2 = -3.0e38f, m3 = -3.0e38f;
  for (int i = l; i < n; i += 64) {
    f32x4 r = *(const f32x4*)(R_slab + (rbase + i) * 4);
    m0 = fmaxf(m0, r[0]); m1 = fmaxf(m1, r[1]);
    m2 = fmaxf(m2, r[2]); m3 = fmaxf(m3, r[3]);
  }
#pragma unroll
  for (int off = 1; off < 64; off <<= 1) {
    m0 = fmaxf(m0, __shfl_xor(m0, off));
    m1 = fmaxf(m1, __shfl_xor(m1, off));
    m2 = fmaxf(m2, __shfl_xor(m2, off));
    m3 = fmaxf(m3, __shfl_xor(m3, off));
  }
  float mh = (h < 2) ? ((h == 0) ? m0 : m1) : ((h == 2) ? m2 : m3);
  float s = 0.f, acc = 0.f;
#pragma unroll 2
  for (int i = 0; i < n; ++i) {
    unsigned pr = pay[rbase + i];
    int dst = (int)(pr & 0xFFFFu);
    int re = (int)(pr >> 16);
    float rv = R_slab[(rbase + i) * 4 + h];
    float bt = beta[re * 4 + h];
    float v = Va[(size_t)dst * 64 + l];
    float pw = __expf(rv - mh);
    s += pw;
    acc += pw * bt * v;
  }
  au[(size_t)wid * 64 + l] = acc / (s + 1e-16f);
}

// ---- out = atom_update @ wo + bo ------------------------------------------
__global__ __launch_bounds__(256) void k_out(
    const float* __restrict__ au, const float* __restrict__ wo,
    const float* __restrict__ bo, float* __restrict__ out) {
  int t = blockIdx.x * blockDim.x + threadIdx.x;
  if (t >= N_ATOM * 16) return;
  int a = t >> 4, c = t & 15;
  float acc = bo[c];
  const float* r = au + (size_t)a * 64;
#pragma unroll
  for (int j = 0; j < 64; ++j) acc += r[j] * wo[j * 16 + c];
  out[t] = acc;
}

extern "C" void kernel_launch(void* const* d_in, const int* in_sizes, int n_in,
                              void* d_out, int out_size, void* d_ws,
                              size_t ws_size, hipStream_t stream) {
  const float* nf   = (const float*)d_in[0];
  const float* ref_ = (const float*)d_in[1];
  const int*   rei  = (const int*)d_in[2];
  const float* af   = (const float*)d_in[3];
  const float* co   = (const float*)d_in[4];
  const int*   cei  = (const int*)d_in[5];
  const int*   aer  = (const int*)d_in[6];
  const float* rw1  = (const float*)d_in[7];
  const float* rb1  = (const float*)d_in[8];
  const float* rw2  = (const float*)d_in[9];
  const float* rb2  = (const float*)d_in[10];
  const float* rw3  = (const float*)d_in[11];
  const float* rb3  = (const float*)d_in[12];
  const float* w1   = (const float*)d_in[13];
  const float* b1   = (const float*)d_in[14];
  const float* w2   = (const float*)d_in[15];
  const float* b2   = (const float*)d_in[16];
  const float* wq   = (const float*)d_in[17];
  const float* bq   = (const float*)d_in[18];
  const float* wkv  = (const float*)d_in[19];
  const float* bkv  = (const float*)d_in[20];
  const float* wo   = (const float*)d_in[21];
  const float* bo   = (const float*)d_in[22];
  float* out = (float*)d_out;

  float* ws = (float*)d_ws;
  float*    Qa      = ws;                            //  896000
  float*    Ka      = Qa + 896000;                   //  896000
  float*    Va      = Ka + 896000;                   //  896000
  float*    rlb     = Va + 896000;                   //   16000
  float*    R_slab  = rlb + 16000;                   // 7168000
  unsigned* pay     = (unsigned*)(R_slab + 7168000); // 1792000
  float*    br_g    = (float*)(pay + 1792000);       //  512000 (32*16000)
  int*      cntg    = (int*)(br_g + 512000);         //  128000 (32*4000)
  int*      cnt_src = cntg + 128000;                 //   14000 [zero]
  float*    block_r = (float*)(cnt_src + 14000);     //   16000
  // overlays (dead after k_edgeR / k_src):
  float*    au      = Qa;                            //  896000
  float*    beta    = Ka + 16000;                    //   16000

  hipMemsetAsync((void*)cnt_src, 0, 14000 * 4, stream);

  kA<<<BUILD_BLKS + PROJ_BLKS + RLB_BLKS, 256, 0, stream>>>(
      cei, aer, cnt_src, pay, af, wq, bq, wkv, bkv, Qa, Ka, Va, ref_, nf, rei,
      w1, b1, w2, b2, rlb);
  k_edgeR<<<N_ATOM / 2, 256, 0, stream>>>(cnt_src, pay, co, Qa, Ka, rlb, rw1,
                                          rb1, rw2, rb2, rw3, rb3, R_slab);
  k_re2<<<NBRE, 1024, 0, stream>>>(cnt_src, pay, R_slab, cntg, br_g);
  k_red<<<(E_RES * 4 + 255) / 256, 256, 0, stream>>>(br_g, cntg, block_r);
  k_br23<<<1, 1024, 0, stream>>>(block_r, rei, beta);
  k_src<<<(N_ATOM * 64 + 255) / 256, 256, 0, stream>>>(cnt_src, pay, R_slab,
                                                       beta, Va, au);
  k_out<<<(N_ATOM * 16 + 255) / 256, 256, 0, stream>>>(au, wo, bo, out);
}

// Round 8
// 296.534 us; speedup vs baseline: 1.4067x; 1.4067x over previous
//
#include <hip/hip_runtime.h>

#define NH 4
#define N_RES 1000
#define E_RES 4000
#define N_ATOM 14000
#define E_ATOM 784000
#define MAXS 128   // src-slab slots/atom (Poisson λ=56, 128 is ~9.6σ)
#define NBRE 256   // blocks for k_re2 (1 per CU)

#define BUILD_BLKS ((E_ATOM + 255) / 256)       // 3063
#define PROJ_BLKS ((N_ATOM * 192 + 255) / 256)  // 10500
#define RLB_BLKS (E_RES / 4)                    // 1000

typedef float f32x4 __attribute__((ext_vector_type(4)));

__device__ __forceinline__ unsigned enc_f(float f) {
  unsigned u = __float_as_uint(f);
  return (u & 0x80000000u) ? ~u : (u | 0x80000000u);
}
__device__ __forceinline__ float dec_f(unsigned e) {
  unsigned u = (e & 0x80000000u) ? (e & 0x7FFFFFFFu) : ~e;
  return __uint_as_float(u);
}

// ---- fused: slab build (src side only) + Q/K/V proj + res_level_bias ------
__global__ __launch_bounds__(256) void kA(
    const int* __restrict__ cei, const int* __restrict__ aer,
    int* __restrict__ cnt_src, unsigned* __restrict__ pay,
    const float* __restrict__ af, const float* __restrict__ wq,
    const float* __restrict__ bq, const float* __restrict__ wkv,
    const float* __restrict__ bkv, float* __restrict__ Qa,
    float* __restrict__ Ka, float* __restrict__ Va,
    const float* __restrict__ ref_, const float* __restrict__ nf,
    const int* __restrict__ rei, const float* __restrict__ w1,
    const float* __restrict__ b1, const float* __restrict__ w2,
    const float* __restrict__ b2, float* __restrict__ rlb) {
  int b = blockIdx.x;
  if (b < BUILD_BLKS) {
    int e = b * 256 + threadIdx.x;
    if (e < E_ATOM) {
      int src = cei[E_ATOM + e];
      int dst = cei[e];
      int re = aer[e];
      int slot = atomicAdd(&cnt_src[src], 1);
      if (slot >= MAXS) slot = MAXS - 1;  // statistically unreachable
      pay[(size_t)src * MAXS + slot] = (unsigned)dst | ((unsigned)re << 16);
    }
  } else if (b < BUILD_BLKS + PROJ_BLKS) {
    int tid = (b - BUILD_BLKS) * 256 + threadIdx.x;
    if (tid < N_ATOM * 192) {
      int a = tid / 192, j = tid % 192;
      const float* row = af + a * 16;
      if (j < 64) {
        float acc = bq[j];
#pragma unroll
        for (int i = 0; i < 16; ++i) acc += row[i] * wq[i * 64 + j];
        Qa[a * 64 + j] = acc;
      } else if (j < 128) {
        int jj = j - 64;
        int col = ((jj >> 4) << 5) + (jj & 15);  // head h, k half
        float acc = bkv[col];
#pragma unroll
        for (int i = 0; i < 16; ++i) acc += row[i] * wkv[i * 128 + col];
        Ka[a * 64 + jj] = acc;
      } else {
        int jj = j - 128;
        int col = ((jj >> 4) << 5) + 16 + (jj & 15);  // head h, v half
        float acc = bkv[col];
#pragma unroll
        for (int i = 0; i < 16; ++i) acc += row[i] * wkv[i * 128 + col];
        Va[a * 64 + jj] = acc;
      }
    }
  } else {
    __shared__ float hid[4][16];
    int sub = threadIdx.x >> 6, l = threadIdx.x & 63;
    int r = (b - BUILD_BLKS - PROJ_BLKS) * 4 + sub;
    int r0 = rei[r], r1 = rei[E_RES + r];
    int j = l >> 2, pq = l & 3;
    float acc = 0.f;
    for (int i = pq; i < 320; i += 4) {
      float cc;
      if (i < 64) cc = ref_[r * 64 + i];
      else if (i < 192) cc = nf[r0 * 128 + (i - 64)];
      else cc = nf[r1 * 128 + (i - 192)];
      acc += cc * w1[i * 16 + j];
    }
    acc += __shfl_xor(acc, 1);
    acc += __shfl_xor(acc, 2);
    if (pq == 0) hid[sub][j] = fmaxf(acc + b1[j], 0.f);
    __syncthreads();
    if (l < 4) {
      float o = b2[l];
#pragma unroll
      for (int jj = 0; jj < 16; ++jj) o += hid[sub][jj] * w2[jj * 4 + l];
      rlb[r * 4 + l] = o;
    }
  }
}

// ---- per-edge R over slab slots (2 atoms per 256-block) -------------------
__global__ __launch_bounds__(256) void k_edgeR(
    const int* __restrict__ cnt_src, const unsigned* __restrict__ pay,
    const float* __restrict__ coords, const float* __restrict__ Qa,
    const float* __restrict__ Ka, const float* __restrict__ rlb,
    const float* __restrict__ rw1, const float* __restrict__ rb1,
    const float* __restrict__ rw2, const float* __restrict__ rb2,
    const float* __restrict__ rw3, const float* __restrict__ rb3,
    float* __restrict__ R_slab) {
  __shared__ float sw1[256], sw2[256], sw3[64], sb1[16], sb2[16], sb3[4];
  int l = threadIdx.x;
  sw1[l] = rw1[l];
  sw2[l] = rw2[l];
  if (l < 64) sw3[l] = rw3[l];
  if (l < 16) { sb1[l] = rb1[l]; sb2[l] = rb2[l]; }
  if (l < 4) sb3[l] = rb3[l];
  __syncthreads();
  int a = blockIdx.x * 2 + (l >> 7);
  int s = l & 127;
  int n = cnt_src[a];
  if (n > MAXS) n = MAXS;
  if (s >= n) return;
  unsigned pr = pay[(size_t)a * MAXS + s];
  int dst = (int)(pr & 0xFFFFu);
  int re = (int)(pr >> 16);
  float vx = coords[dst * 3 + 0] - coords[a * 3 + 0] + 1e-8f;
  float vy = coords[dst * 3 + 1] - coords[a * 3 + 1] + 1e-8f;
  float vz = coords[dst * 3 + 2] - coords[a * 3 + 2] + 1e-8f;
  float d = sqrtf(vx * vx + vy * vy + vz * vz);
  float rb[16], h1[16], h2[16];
  const float step = 20.0f / 15.0f;
  const float inv_sigma = 1.0f / 1.25f;
#pragma unroll
  for (int jj = 0; jj < 16; ++jj) {
    float t = (d - jj * step) * inv_sigma;
    rb[jj] = __expf(-t * t);
  }
#pragma unroll
  for (int k = 0; k < 16; ++k) {
    float acc = sb1[k];
#pragma unroll
    for (int jj = 0; jj < 16; ++jj) acc += rb[jj] * sw1[jj * 16 + k];
    h1[k] = fmaxf(acc, 0.f);
  }
#pragma unroll
  for (int k = 0; k < 16; ++k) {
    float acc = sb2[k];
#pragma unroll
    for (int jj = 0; jj < 16; ++jj) acc += h1[jj] * sw2[jj * 16 + k];
    h2[k] = fmaxf(acc, 0.f);
  }
  const float4* qp = (const float4*)(Qa + (size_t)a * 64);
  const float4* kp = (const float4*)(Ka + (size_t)dst * 64);
  float4 rlb4 = *(const float4*)(rlb + re * 4);
  const float* rlbp = (const float*)&rlb4;
  f32x4 Rv;
#pragma unroll
  for (int h = 0; h < NH; ++h) {
    float adb = sb3[h];
#pragma unroll
    for (int jj = 0; jj < 16; ++jj) adb += h2[jj] * sw3[jj * 4 + h];
    float dot = 0.f;
#pragma unroll
    for (int v4 = 0; v4 < 4; ++v4) {
      float4 q4 = qp[h * 4 + v4];
      float4 k4 = kp[h * 4 + v4];
      dot += q4.x * k4.x + q4.y * k4.y + q4.z * k4.z + q4.w * k4.w;
    }
    Rv[h] = dot * 0.25f + rlbp[h] + adb;
  }
  __builtin_nontemporal_store(Rv,
                              (f32x4*)(R_slab + (size_t)(a * MAXS + s) * 4));
}

// ---- per-re sums via LDS-replicated accumulators, 256 blocks --------------
__global__ __launch_bounds__(1024) void k_re2(
    const int* __restrict__ cnt_src, const unsigned* __restrict__ pay,
    const float* __restrict__ R_slab, int* __restrict__ cntg,
    float* __restrict__ br_g) {
  __shared__ __align__(16) unsigned char smraw[64000];
  int* scnt = (int*)smraw;
  float* sbr = (float*)smraw;
  int tid = threadIdx.x;
  int bid = blockIdx.x;
  int wv = tid >> 6, lane = tid & 63;
  int gw = bid * 16 + wv;  // global wave id, 4096 waves total
  // stage 1: counts per re
  for (int j = tid; j < E_RES; j += 1024) scnt[j] = 0;
  __syncthreads();
  for (int a = gw; a < N_ATOM; a += NBRE * 16) {
    int n = cnt_src[a];
    if (n > MAXS) n = MAXS;
    size_t base = (size_t)a * MAXS;
    for (int i = lane; i < n; i += 64) {
      int re = (int)(pay[base + i] >> 16);
      atomicAdd(&scnt[re], 1);
    }
  }
  __syncthreads();
  for (int j = tid; j < E_RES; j += 1024) cntg[bid * E_RES + j] = scnt[j];
  __syncthreads();
  // stage 2: per-re, per-head R sums
  for (int j = tid; j < E_RES * 4; j += 1024) sbr[j] = 0.f;
  __syncthreads();
  for (int a = gw; a < N_ATOM; a += NBRE * 16) {
    int n = cnt_src[a];
    if (n > MAXS) n = MAXS;
    size_t base = (size_t)a * MAXS;
    for (int i = lane; i < n; i += 64) {
      int re = (int)(pay[base + i] >> 16);
      f32x4 r = *(const f32x4*)(R_slab + (base + i) * 4);
      atomicAdd(&sbr[re * 4 + 0], r[0]);
      atomicAdd(&sbr[re * 4 + 1], r[1]);
      atomicAdd(&sbr[re * 4 + 2], r[2]);
      atomicAdd(&sbr[re * 4 + 3], r[3]);
    }
  }
  __syncthreads();
  for (int j = tid; j < E_RES * 4; j += 1024)
    br_g[(size_t)bid * E_RES * 4 + j] = sbr[j];
}

// ---- reduce the 256 copies -> block_r (already divided by count) ----------
__global__ __launch_bounds__(256) void k_red(const float* __restrict__ br_g,
                                             const int* __restrict__ cntg,
                                             float* __restrict__ block_r) {
  int t = blockIdx.x * blockDim.x + threadIdx.x;
  if (t >= E_RES * 4) return;
  int r = t >> 2;
  float s = 0.f;
  int c = 0;
  for (int b = 0; b < NBRE; ++b) {
    s += br_g[(size_t)b * E_RES * 4 + t];
    c += cntg[b * E_RES + r];
  }
  block_r[t] = s / fmaxf((float)c, 1.0f);
}

// ---- residue softmax (max, denom, beta) fully in LDS, single block --------
__global__ __launch_bounds__(1024) void k_br23(
    const float* __restrict__ block_r, const int* __restrict__ rei,
    float* __restrict__ beta) {
  __shared__ unsigned resm[N_RES * 4];
  __shared__ float ress[N_RES * 4];
  int tid = threadIdx.x;
  for (int j = tid; j < N_RES * 4; j += 1024) { resm[j] = 0u; ress[j] = 0.f; }
  __syncthreads();
  float brv[4][4];
  int r1v[4];
  for (int k = 0; k < 4; ++k) {
    int r = tid + k * 1024;
    if (r < E_RES) {
      r1v[k] = rei[E_RES + r];
#pragma unroll
      for (int h = 0; h < 4; ++h) {
        brv[k][h] = block_r[r * 4 + h];
        atomicMax(&resm[r1v[k] * 4 + h], enc_f(brv[k][h]));
      }
    }
  }
  __syncthreads();
  for (int k = 0; k < 4; ++k) {
    int r = tid + k * 1024;
    if (r < E_RES) {
#pragma unroll
      for (int h = 0; h < 4; ++h)
        atomicAdd(&ress[r1v[k] * 4 + h],
                  __expf(brv[k][h] - dec_f(resm[r1v[k] * 4 + h])));
    }
  }
  __syncthreads();
  for (int k = 0; k < 4; ++k) {
    int r = tid + k * 1024;
    if (r < E_RES) {
#pragma unroll
      for (int h = 0; h < 4; ++h)
        beta[r * 4 + h] = __expf(brv[k][h] - dec_f(resm[r1v[k] * 4 + h])) /
                          (ress[r1v[k] * 4 + h] + 1e-16f);
    }
  }
}

// ---- per src atom: exact 2-pass softmax + weighted V ----------------------
__global__ __launch_bounds__(256) void k_src(
    const int* __restrict__ cnt_src, const unsigned* __restrict__ pay,
    const float* __restrict__ R_slab, const float* __restrict__ beta,
    const float* __restrict__ Va, float* __restrict__ au) {
  int wid = (blockIdx.x * blockDim.x + threadIdx.x) >> 6;
  int l = threadIdx.x & 63;
  if (wid >= N_ATOM) return;
  int n = cnt_src[wid];
  if (n > MAXS) n = MAXS;
  int h = l >> 4;
  size_t rbase = (size_t)wid * MAXS;
  float m0 = -3.0e38f, m1 = -3.0e38f, m2 = -3.0e38f, m3 = -3.0e38f;
  for (int i = l; i < n; i += 64) {
    f32x4 r = *(const f32x4*)(R_slab + (rbase + i) * 4);
    m0 = fmaxf(m0, r[0]); m1 = fmaxf(m1, r[1]);
    m2 = fmaxf(m2, r[2]); m3 = fmaxf(m3, r[3]);
  }
#pragma unroll
  for (int off = 1; off < 64; off <<= 1) {
    m0 = fmaxf(m0, __shfl_xor(m0, off));
    m1 = fmaxf(m1, __shfl_xor(m1, off));
    m2 = fmaxf(m2, __shfl_xor(m2, off));
    m3 = fmaxf(m3, __shfl_xor(m3, off));
  }
  float mh = (h < 2) ? ((h == 0) ? m0 : m1) : ((h == 2) ? m2 : m3);
  float s = 0.f, acc = 0.f;
#pragma unroll 2
  for (int i = 0; i < n; ++i) {
    unsigned pr = pay[rbase + i];
    int dst = (int)(pr & 0xFFFFu);
    int re = (int)(pr >> 16);
    float rv = R_slab[(rbase + i) * 4 + h];
    float bt = beta[re * 4 + h];
    float v = Va[(size_t)dst * 64 + l];
    float pw = __expf(rv - mh);
    s += pw;
    acc += pw * bt * v;
  }
  au[(size_t)wid * 64 + l] = acc / (s + 1e-16f);
}

// ---- out = atom_update @ wo + bo ------------------------------------------
__global__ __launch_bounds__(256) void k_out(
    const float* __restrict__ au, const float* __restrict__ wo,
    const float* __restrict__ bo, float* __restrict__ out) {
  int t = blockIdx.x * blockDim.x + threadIdx.x;
  if (t >= N_ATOM * 16) return;
  int a = t >> 4, c = t & 15;
  float acc = bo[c];
  const float* r = au + (size_t)a * 64;
#pragma unroll
  for (int j = 0; j < 64; ++j) acc += r[j] * wo[j * 16 + c];
  out[t] = acc;
}

extern "C" void kernel_launch(void* const* d_in, const int* in_sizes, int n_in,
                              void* d_out, int out_size, void* d_ws,
                              size_t ws_size, hipStream_t stream) {
  const float* nf   = (const float*)d_in[0];
  const float* ref_ = (const float*)d_in[1];
  const int*   rei  = (const int*)d_in[2];
  const float* af   = (const float*)d_in[3];
  const float* co   = (const float*)d_in[4];
  const int*   cei  = (const int*)d_in[5];
  const int*   aer  = (const int*)d_in[6];
  const float* rw1  = (const float*)d_in[7];
  const float* rb1  = (const float*)d_in[8];
  const float* rw2  = (const float*)d_in[9];
  const float* rb2  = (const float*)d_in[10];
  const float* rw3  = (const float*)d_in[11];
  const float* rb3  = (const float*)d_in[12];
  const float* w1   = (const float*)d_in[13];
  const float* b1   = (const float*)d_in[14];
  const float* w2   = (const float*)d_in[15];
  const float* b2   = (const float*)d_in[16];
  const float* wq   = (const float*)d_in[17];
  const float* bq   = (const float*)d_in[18];
  const float* wkv  = (const float*)d_in[19];
  const float* bkv  = (const float*)d_in[20];
  const float* wo   = (const float*)d_in[21];
  const float* bo   = (const float*)d_in[22];
  float* out = (float*)d_out;

  float* ws = (float*)d_ws;
  float*    Qa      = ws;                            //  896000
  float*    Ka      = Qa + 896000;                   //  896000
  float*    Va      = Ka + 896000;                   //  896000
  float*    rlb     = Va + 896000;                   //   16000
  float*    R_slab  = rlb + 16000;                   // 7168000
  unsigned* pay     = (unsigned*)(R_slab + 7168000); // 1792000
  float*    br_g    = (float*)(pay + 1792000);       // 4096000 (256*16000)
  int*      cntg    = (int*)(br_g + 4096000);        // 1024000 (256*4000)
  int*      cnt_src = cntg + 1024000;                //   14000 [zero]
  float*    block_r = (float*)(cnt_src + 14000);     //   16000
  // overlays (dead after k_edgeR / k_src):
  float*    au      = Qa;                            //  896000
  float*    beta    = Ka + 16000;                    //   16000

  hipMemsetAsync((void*)cnt_src, 0, 14000 * 4, stream);

  kA<<<BUILD_BLKS + PROJ_BLKS + RLB_BLKS, 256, 0, stream>>>(
      cei, aer, cnt_src, pay, af, wq, bq, wkv, bkv, Qa, Ka, Va, ref_, nf, rei,
      w1, b1, w2, b2, rlb);
  k_edgeR<<<N_ATOM / 2, 256, 0, stream>>>(cnt_src, pay, co, Qa, Ka, rlb, rw1,
                                          rb1, rw2, rb2, rw3, rb3, R_slab);
  k_re2<<<NBRE, 1024, 0, stream>>>(cnt_src, pay, R_slab, cntg, br_g);
  k_red<<<(E_RES * 4 + 255) / 256, 256, 0, stream>>>(br_g, cntg, block_r);
  k_br23<<<1, 1024, 0, stream>>>(block_r, rei, beta);
  k_src<<<(N_ATOM * 64 + 255) / 256, 256, 0, stream>>>(cnt_src, pay, R_slab,
                                                       beta, Va, au);
  k_out<<<(N_ATOM * 16 + 255) / 256, 256, 0, stream>>>(au, wo, bo, out);
}

// Round 9
// 258.424 us; speedup vs baseline: 1.6142x; 1.1475x over previous
//
#include <hip/hip_runtime.h>

#define NH 4
#define N_RES 1000
#define E_RES 4000
#define N_ATOM 14000
#define E_ATOM 784000
#define MAXS 128    // src-slab slots/atom (Poisson λ=56, 128 is ~9.6σ)
#define NBRE 256    // blocks for k_re2 (1 per CU)
#define TABN 16385  // dist-bias table entries over [0,32], Δ=1/512
#define TINV 512.0f

#define BUILD_BLKS ((E_ATOM + 255) / 256)       // 3063
#define PROJ_BLKS ((N_ATOM * 192 + 255) / 256)  // 10500
#define RLB_BLKS (E_RES / 4)                    // 1000
#define TAB_BLKS ((TABN + 255) / 256)           // 65

typedef float f32x4 __attribute__((ext_vector_type(4)));

__device__ __forceinline__ unsigned enc_f(float f) {
  unsigned u = __float_as_uint(f);
  return (u & 0x80000000u) ? ~u : (u | 0x80000000u);
}
__device__ __forceinline__ float dec_f(unsigned e) {
  unsigned u = (e & 0x80000000u) ? (e & 0x7FFFFFFFu) : ~e;
  return __uint_as_float(u);
}

// ---- fused: slab build + Q/K/V proj + res_level_bias + dist-bias table ----
__global__ __launch_bounds__(256) void kA(
    const int* __restrict__ cei, const int* __restrict__ aer,
    int* __restrict__ cnt_src, unsigned* __restrict__ pay,
    const float* __restrict__ af, const float* __restrict__ wq,
    const float* __restrict__ bq, const float* __restrict__ wkv,
    const float* __restrict__ bkv, float* __restrict__ Qa,
    float* __restrict__ Ka, float* __restrict__ Va,
    const float* __restrict__ ref_, const float* __restrict__ nf,
    const int* __restrict__ rei, const float* __restrict__ w1,
    const float* __restrict__ b1, const float* __restrict__ w2,
    const float* __restrict__ b2, float* __restrict__ rlb,
    const float* __restrict__ rw1, const float* __restrict__ rb1,
    const float* __restrict__ rw2, const float* __restrict__ rb2,
    const float* __restrict__ rw3, const float* __restrict__ rb3,
    f32x4* __restrict__ tab) {
  int b = blockIdx.x;
  if (b < BUILD_BLKS) {
    int e = b * 256 + threadIdx.x;
    if (e < E_ATOM) {
      int src = cei[E_ATOM + e];
      int dst = cei[e];
      int re = aer[e];
      int slot = atomicAdd(&cnt_src[src], 1);
      if (slot >= MAXS) slot = MAXS - 1;  // statistically unreachable
      pay[(size_t)src * MAXS + slot] = (unsigned)dst | ((unsigned)re << 16);
    }
  } else if (b < BUILD_BLKS + PROJ_BLKS) {
    int tid = (b - BUILD_BLKS) * 256 + threadIdx.x;
    if (tid < N_ATOM * 192) {
      int a = tid / 192, j = tid % 192;
      const float* row = af + a * 16;
      if (j < 64) {
        float acc = bq[j];
#pragma unroll
        for (int i = 0; i < 16; ++i) acc += row[i] * wq[i * 64 + j];
        Qa[a * 64 + j] = acc;
      } else if (j < 128) {
        int jj = j - 64;
        int col = ((jj >> 4) << 5) + (jj & 15);  // head h, k half
        float acc = bkv[col];
#pragma unroll
        for (int i = 0; i < 16; ++i) acc += row[i] * wkv[i * 128 + col];
        Ka[a * 64 + jj] = acc;
      } else {
        int jj = j - 128;
        int col = ((jj >> 4) << 5) + 16 + (jj & 15);  // head h, v half
        float acc = bkv[col];
#pragma unroll
        for (int i = 0; i < 16; ++i) acc += row[i] * wkv[i * 128 + col];
        Va[a * 64 + jj] = acc;
      }
    }
  } else if (b < BUILD_BLKS + PROJ_BLKS + RLB_BLKS) {
    __shared__ float hid[4][16];
    int sub = threadIdx.x >> 6, l = threadIdx.x & 63;
    int r = (b - BUILD_BLKS - PROJ_BLKS) * 4 + sub;
    int r0 = rei[r], r1 = rei[E_RES + r];
    int j = l >> 2, pq = l & 3;
    float acc = 0.f;
    for (int i = pq; i < 320; i += 4) {
      float cc;
      if (i < 64) cc = ref_[r * 64 + i];
      else if (i < 192) cc = nf[r0 * 128 + (i - 64)];
      else cc = nf[r1 * 128 + (i - 192)];
      acc += cc * w1[i * 16 + j];
    }
    acc += __shfl_xor(acc, 1);
    acc += __shfl_xor(acc, 2);
    if (pq == 0) hid[sub][j] = fmaxf(acc + b1[j], 0.f);
    __syncthreads();
    if (l < 4) {
      float o = b2[l];
#pragma unroll
      for (int jj = 0; jj < 16; ++jj) o += hid[sub][jj] * w2[jj * 4 + l];
      rlb[r * 4 + l] = o;
    }
  } else {
    // dist-bias lookup table: tab[i] = MLP3(MLP2(MLP1(rbf(i/512))))
    int i = (b - BUILD_BLKS - PROJ_BLKS - RLB_BLKS) * 256 + threadIdx.x;
    if (i < TABN) {
      float d = (float)i * (1.0f / TINV);
      float rb[16], h1[16], h2[16];
      const float step = 20.0f / 15.0f;
      const float inv_sigma = 1.0f / 1.25f;
#pragma unroll
      for (int jj = 0; jj < 16; ++jj) {
        float t = (d - jj * step) * inv_sigma;
        rb[jj] = __expf(-t * t);
      }
#pragma unroll
      for (int k = 0; k < 16; ++k) {
        float acc = rb1[k];
#pragma unroll
        for (int jj = 0; jj < 16; ++jj) acc += rb[jj] * rw1[jj * 16 + k];
        h1[k] = fmaxf(acc, 0.f);
      }
#pragma unroll
      for (int k = 0; k < 16; ++k) {
        float acc = rb2[k];
#pragma unroll
        for (int jj = 0; jj < 16; ++jj) acc += h1[jj] * rw2[jj * 16 + k];
        h2[k] = fmaxf(acc, 0.f);
      }
      f32x4 o;
#pragma unroll
      for (int h = 0; h < NH; ++h) {
        float acc = rb3[h];
#pragma unroll
        for (int jj = 0; jj < 16; ++jj) acc += h2[jj] * rw3[jj * 4 + h];
        o[h] = acc;
      }
      tab[i] = o;
    }
  }
}

// ---- per-edge R: table-lerp dist bias + q.k dots (2 atoms per block) ------
__global__ __launch_bounds__(256) void k_edgeR(
    const int* __restrict__ cnt_src, const unsigned* __restrict__ pay,
    const float* __restrict__ coords, const float* __restrict__ Qa,
    const float* __restrict__ Ka, const float* __restrict__ rlb,
    const f32x4* __restrict__ tab, float* __restrict__ R_slab) {
  int l = threadIdx.x;
  int a = blockIdx.x * 2 + (l >> 7);
  int s = l & 127;
  int n = cnt_src[a];
  if (n > MAXS) n = MAXS;
  if (s >= n) return;
  unsigned pr = pay[(size_t)a * MAXS + s];
  int dst = (int)(pr & 0xFFFFu);
  int re = (int)(pr >> 16);
  float vx = coords[dst * 3 + 0] - coords[a * 3 + 0] + 1e-8f;
  float vy = coords[dst * 3 + 1] - coords[a * 3 + 1] + 1e-8f;
  float vz = coords[dst * 3 + 2] - coords[a * 3 + 2] + 1e-8f;
  float d = sqrtf(vx * vx + vy * vy + vz * vz);
  float x = d * TINV;
  int i = (int)x;
  if (i > TABN - 2) i = TABN - 2;
  float fr = x - (float)i;
  f32x4 t0 = tab[i], t1 = tab[i + 1];
  f32x4 adb = t0 + (t1 - t0) * fr;
  const float4* qp = (const float4*)(Qa + (size_t)a * 64);
  const float4* kp = (const float4*)(Ka + (size_t)dst * 64);
  float4 rlb4 = *(const float4*)(rlb + re * 4);
  const float* rlbp = (const float*)&rlb4;
  f32x4 Rv;
#pragma unroll
  for (int h = 0; h < NH; ++h) {
    float dot = 0.f;
#pragma unroll
    for (int v4 = 0; v4 < 4; ++v4) {
      float4 q4 = qp[h * 4 + v4];
      float4 k4 = kp[h * 4 + v4];
      dot += q4.x * k4.x + q4.y * k4.y + q4.z * k4.z + q4.w * k4.w;
    }
    Rv[h] = dot * 0.25f + rlbp[h] + adb[h];
  }
  __builtin_nontemporal_store(Rv,
                              (f32x4*)(R_slab + (size_t)(a * MAXS + s) * 4));
}

// ---- per-re sums via LDS-replicated accumulators, 256 blocks --------------
__global__ __launch_bounds__(1024) void k_re2(
    const int* __restrict__ cnt_src, const unsigned* __restrict__ pay,
    const float* __restrict__ R_slab, int* __restrict__ cntg,
    float* __restrict__ br_g) {
  __shared__ __align__(16) unsigned char smraw[64000];
  int* scnt = (int*)smraw;
  float* sbr = (float*)smraw;
  int tid = threadIdx.x;
  int bid = blockIdx.x;
  int wv = tid >> 6, lane = tid & 63;
  int gw = bid * 16 + wv;  // global wave id
  for (int j = tid; j < E_RES; j += 1024) scnt[j] = 0;
  __syncthreads();
  for (int a = gw; a < N_ATOM; a += NBRE * 16) {
    int n = cnt_src[a];
    if (n > MAXS) n = MAXS;
    size_t base = (size_t)a * MAXS;
    for (int i = lane; i < n; i += 64) {
      int re = (int)(pay[base + i] >> 16);
      atomicAdd(&scnt[re], 1);
    }
  }
  __syncthreads();
  for (int j = tid; j < E_RES; j += 1024) cntg[bid * E_RES + j] = scnt[j];
  __syncthreads();
  for (int j = tid; j < E_RES * 4; j += 1024) sbr[j] = 0.f;
  __syncthreads();
  for (int a = gw; a < N_ATOM; a += NBRE * 16) {
    int n = cnt_src[a];
    if (n > MAXS) n = MAXS;
    size_t base = (size_t)a * MAXS;
    for (int i = lane; i < n; i += 64) {
      int re = (int)(pay[base + i] >> 16);
      f32x4 r = *(const f32x4*)(R_slab + (base + i) * 4);
      atomicAdd(&sbr[re * 4 + 0], r[0]);
      atomicAdd(&sbr[re * 4 + 1], r[1]);
      atomicAdd(&sbr[re * 4 + 2], r[2]);
      atomicAdd(&sbr[re * 4 + 3], r[3]);
    }
  }
  __syncthreads();
  for (int j = tid; j < E_RES * 4; j += 1024)
    br_g[(size_t)bid * E_RES * 4 + j] = sbr[j];
}

// ---- reduce the 256 copies -> block_r (already divided by count) ----------
__global__ __launch_bounds__(256) void k_red(const float* __restrict__ br_g,
                                             const int* __restrict__ cntg,
                                             float* __restrict__ block_r) {
  int t = blockIdx.x * blockDim.x + threadIdx.x;
  if (t >= E_RES * 4) return;
  int r = t >> 2;
  float s = 0.f;
  int c = 0;
  for (int b = 0; b < NBRE; ++b) {
    s += br_g[(size_t)b * E_RES * 4 + t];
    c += cntg[b * E_RES + r];
  }
  block_r[t] = s / fmaxf((float)c, 1.0f);
}

// ---- residue softmax (max, denom, beta) fully in LDS, single block --------
__global__ __launch_bounds__(1024) void k_br23(
    const float* __restrict__ block_r, const int* __restrict__ rei,
    float* __restrict__ beta) {
  __shared__ unsigned resm[N_RES * 4];
  __shared__ float ress[N_RES * 4];
  int tid = threadIdx.x;
  for (int j = tid; j < N_RES * 4; j += 1024) { resm[j] = 0u; ress[j] = 0.f; }
  __syncthreads();
  float brv[4][4];
  int r1v[4];
  for (int k = 0; k < 4; ++k) {
    int r = tid + k * 1024;
    if (r < E_RES) {
      r1v[k] = rei[E_RES + r];
#pragma unroll
      for (int h = 0; h < 4; ++h) {
        brv[k][h] = block_r[r * 4 + h];
        atomicMax(&resm[r1v[k] * 4 + h], enc_f(brv[k][h]));
      }
    }
  }
  __syncthreads();
  for (int k = 0; k < 4; ++k) {
    int r = tid + k * 1024;
    if (r < E_RES) {
#pragma unroll
      for (int h = 0; h < 4; ++h)
        atomicAdd(&ress[r1v[k] * 4 + h],
                  __expf(brv[k][h] - dec_f(resm[r1v[k] * 4 + h])));
    }
  }
  __syncthreads();
  for (int k = 0; k < 4; ++k) {
    int r = tid + k * 1024;
    if (r < E_RES) {
#pragma unroll
      for (int h = 0; h < 4; ++h)
        beta[r * 4 + h] = __expf(brv[k][h] - dec_f(resm[r1v[k] * 4 + h])) /
                          (ress[r1v[k] * 4 + h] + 1e-16f);
    }
  }
}

// ---- per src atom: exact 2-pass softmax + weighted V ----------------------
__global__ __launch_bounds__(256) void k_src(
    const int* __restrict__ cnt_src, const unsigned* __restrict__ pay,
    const float* __restrict__ R_slab, const float* __restrict__ beta,
    const float* __restrict__ Va, float* __restrict__ au) {
  int wid = (blockIdx.x * blockDim.x + threadIdx.x) >> 6;
  int l = threadIdx.x & 63;
  if (wid >= N_ATOM) return;
  int n = cnt_src[wid];
  if (n > MAXS) n = MAXS;
  int h = l >> 4;
  size_t rbase = (size_t)wid * MAXS;
  float m0 = -3.0e38f, m1 = -3.0e38f, m2 = -3.0e38f, m3 = -3.0e38f;
  for (int i = l; i < n; i += 64) {
    f32x4 r = *(const f32x4*)(R_slab + (rbase + i) * 4);
    m0 = fmaxf(m0, r[0]); m1 = fmaxf(m1, r[1]);
    m2 = fmaxf(m2, r[2]); m3 = fmaxf(m3, r[3]);
  }
#pragma unroll
  for (int off = 1; off < 64; off <<= 1) {
    m0 = fmaxf(m0, __shfl_xor(m0, off));
    m1 = fmaxf(m1, __shfl_xor(m1, off));
    m2 = fmaxf(m2, __shfl_xor(m2, off));
    m3 = fmaxf(m3, __shfl_xor(m3, off));
  }
  float mh = (h < 2) ? ((h == 0) ? m0 : m1) : ((h == 2) ? m2 : m3);
  float s = 0.f, acc = 0.f;
#pragma unroll 2
  for (int i = 0; i < n; ++i) {
    unsigned pr = pay[rbase + i];
    int dst = (int)(pr & 0xFFFFu);
    int re = (int)(pr >> 16);
    float rv = R_slab[(rbase + i) * 4 + h];
    float bt = beta[re * 4 + h];
    float v = Va[(size_t)dst * 64 + l];
    float pw = __expf(rv - mh);
    s += pw;
    acc += pw * bt * v;
  }
  au[(size_t)wid * 64 + l] = acc / (s + 1e-16f);
}

// ---- out = atom_update @ wo + bo ------------------------------------------
__global__ __launch_bounds__(256) void k_out(
    const float* __restrict__ au, const float* __restrict__ wo,
    const float* __restrict__ bo, float* __restrict__ out) {
  int t = blockIdx.x * blockDim.x + threadIdx.x;
  if (t >= N_ATOM * 16) return;
  int a = t >> 4, c = t & 15;
  float acc = bo[c];
  const float* r = au + (size_t)a * 64;
#pragma unroll
  for (int j = 0; j < 64; ++j) acc += r[j] * wo[j * 16 + c];
  out[t] = acc;
}

extern "C" void kernel_launch(void* const* d_in, const int* in_sizes, int n_in,
                              void* d_out, int out_size, void* d_ws,
                              size_t ws_size, hipStream_t stream) {
  const float* nf   = (const float*)d_in[0];
  const float* ref_ = (const float*)d_in[1];
  const int*   rei  = (const int*)d_in[2];
  const float* af   = (const float*)d_in[3];
  const float* co   = (const float*)d_in[4];
  const int*   cei  = (const int*)d_in[5];
  const int*   aer  = (const int*)d_in[6];
  const float* rw1  = (const float*)d_in[7];
  const float* rb1  = (const float*)d_in[8];
  const float* rw2  = (const float*)d_in[9];
  const float* rb2  = (const float*)d_in[10];
  const float* rw3  = (const float*)d_in[11];
  const float* rb3  = (const float*)d_in[12];
  const float* w1   = (const float*)d_in[13];
  const float* b1   = (const float*)d_in[14];
  const float* w2   = (const float*)d_in[15];
  const float* b2   = (const float*)d_in[16];
  const float* wq   = (const float*)d_in[17];
  const float* bq   = (const float*)d_in[18];
  const float* wkv  = (const float*)d_in[19];
  const float* bkv  = (const float*)d_in[20];
  const float* wo   = (const float*)d_in[21];
  const float* bo   = (const float*)d_in[22];
  float* out = (float*)d_out;

  float* ws = (float*)d_ws;
  float*    Qa      = ws;                            //  896000
  float*    Ka      = Qa + 896000;                   //  896000
  float*    Va      = Ka + 896000;                   //  896000
  float*    rlb     = Va + 896000;                   //   16000
  float*    R_slab  = rlb + 16000;                   // 7168000
  unsigned* pay     = (unsigned*)(R_slab + 7168000); // 1792000
  float*    br_g    = (float*)(pay + 1792000);       // 4096000 (256*16000)
  int*      cntg    = (int*)(br_g + 4096000);        // 1024000 (256*4000)
  int*      cnt_src = cntg + 1024000;                //   14000 [zero]
  float*    block_r = (float*)(cnt_src + 14000);     //   16000
  f32x4*    tab     = (f32x4*)(block_r + 16000);     //   65540 floats
  // overlays (dead after k_edgeR / k_src):
  float*    au      = Qa;                            //  896000
  float*    beta    = Ka + 16000;                    //   16000

  hipMemsetAsync((void*)cnt_src, 0, 14000 * 4, stream);

  kA<<<BUILD_BLKS + PROJ_BLKS + RLB_BLKS + TAB_BLKS, 256, 0, stream>>>(
      cei, aer, cnt_src, pay, af, wq, bq, wkv, bkv, Qa, Ka, Va, ref_, nf, rei,
      w1, b1, w2, b2, rlb, rw1, rb1, rw2, rb2, rw3, rb3, tab);
  k_edgeR<<<N_ATOM / 2, 256, 0, stream>>>(cnt_src, pay, co, Qa, Ka, rlb, tab,
                                          R_slab);
  k_re2<<<NBRE, 1024, 0, stream>>>(cnt_src, pay, R_slab, cntg, br_g);
  k_red<<<(E_RES * 4 + 255) / 256, 256, 0, stream>>>(br_g, cntg, block_r);
  k_br23<<<1, 1024, 0, stream>>>(block_r, rei, beta);
  k_src<<<(N_ATOM * 64 + 255) / 256, 256, 0, stream>>>(cnt_src, pay, R_slab,
                                                       beta, Va, au);
  k_out<<<(N_ATOM * 16 + 255) / 256, 256, 0, stream>>>(au, wo, bo, out);
}

// Round 10
// 252.416 us; speedup vs baseline: 1.6526x; 1.0238x over previous
//
#include <hip/hip_runtime.h>

#define NH 4
#define N_RES 1000
#define E_RES 4000
#define N_ATOM 14000
#define E_ATOM 784000
#define MAXS 128    // src-slab slots/atom (Poisson λ=56, 128 is ~9.6σ)
#define NBRE 256    // blocks for k_re2 (1 per CU)
#define TABN 16385  // dist-bias table entries over [0,32], Δ=1/512
#define TINV 512.0f

#define BUILD_BLKS ((E_ATOM + 255) / 256)       // 3063
#define PROJ_BLKS ((N_ATOM * 192 + 255) / 256)  // 10500
#define RLB_BLKS (E_RES / 4)                    // 1000
#define TAB_BLKS ((TABN + 255) / 256)           // 65

typedef float f32x4 __attribute__((ext_vector_type(4)));

__device__ __forceinline__ unsigned enc_f(float f) {
  unsigned u = __float_as_uint(f);
  return (u & 0x80000000u) ? ~u : (u | 0x80000000u);
}
__device__ __forceinline__ float dec_f(unsigned e) {
  unsigned u = (e & 0x80000000u) ? (e & 0x7FFFFFFFu) : ~e;
  return __uint_as_float(u);
}

// ---- fused: slab build + Q/K/V proj + res_level_bias + dist-bias table ----
__global__ __launch_bounds__(256) void kA(
    const int* __restrict__ cei, const int* __restrict__ aer,
    int* __restrict__ cnt_src, unsigned* __restrict__ pay,
    const float* __restrict__ af, const float* __restrict__ wq,
    const float* __restrict__ bq, const float* __restrict__ wkv,
    const float* __restrict__ bkv, float* __restrict__ Qa,
    float* __restrict__ Ka, float* __restrict__ Va,
    const float* __restrict__ ref_, const float* __restrict__ nf,
    const int* __restrict__ rei, const float* __restrict__ w1,
    const float* __restrict__ b1, const float* __restrict__ w2,
    const float* __restrict__ b2, float* __restrict__ rlb,
    const float* __restrict__ rw1, const float* __restrict__ rb1,
    const float* __restrict__ rw2, const float* __restrict__ rb2,
    const float* __restrict__ rw3, const float* __restrict__ rb3,
    f32x4* __restrict__ tab) {
  int b = blockIdx.x;
  if (b < BUILD_BLKS) {
    int e = b * 256 + threadIdx.x;
    if (e < E_ATOM) {
      int src = cei[E_ATOM + e];
      int dst = cei[e];
      int re = aer[e];
      int slot = atomicAdd(&cnt_src[src], 1);
      if (slot >= MAXS) slot = MAXS - 1;  // statistically unreachable
      pay[(size_t)src * MAXS + slot] = (unsigned)dst | ((unsigned)re << 16);
    }
  } else if (b < BUILD_BLKS + PROJ_BLKS) {
    int tid = (b - BUILD_BLKS) * 256 + threadIdx.x;
    if (tid < N_ATOM * 192) {
      int a = tid / 192, j = tid % 192;
      const float* row = af + a * 16;
      if (j < 64) {
        float acc = bq[j];
#pragma unroll
        for (int i = 0; i < 16; ++i) acc += row[i] * wq[i * 64 + j];
        Qa[a * 64 + j] = acc;
      } else if (j < 128) {
        int jj = j - 64;
        int col = ((jj >> 4) << 5) + (jj & 15);  // head h, k half
        float acc = bkv[col];
#pragma unroll
        for (int i = 0; i < 16; ++i) acc += row[i] * wkv[i * 128 + col];
        Ka[a * 64 + jj] = acc;
      } else {
        int jj = j - 128;
        int col = ((jj >> 4) << 5) + 16 + (jj & 15);  // head h, v half
        float acc = bkv[col];
#pragma unroll
        for (int i = 0; i < 16; ++i) acc += row[i] * wkv[i * 128 + col];
        Va[a * 64 + jj] = acc;
      }
    }
  } else if (b < BUILD_BLKS + PROJ_BLKS + RLB_BLKS) {
    __shared__ float hid[4][16];
    int sub = threadIdx.x >> 6, l = threadIdx.x & 63;
    int r = (b - BUILD_BLKS - PROJ_BLKS) * 4 + sub;
    int r0 = rei[r], r1 = rei[E_RES + r];
    int j = l >> 2, pq = l & 3;
    float acc = 0.f;
    for (int i = pq; i < 320; i += 4) {
      float cc;
      if (i < 64) cc = ref_[r * 64 + i];
      else if (i < 192) cc = nf[r0 * 128 + (i - 64)];
      else cc = nf[r1 * 128 + (i - 192)];
      acc += cc * w1[i * 16 + j];
    }
    acc += __shfl_xor(acc, 1);
    acc += __shfl_xor(acc, 2);
    if (pq == 0) hid[sub][j] = fmaxf(acc + b1[j], 0.f);
    __syncthreads();
    if (l < 4) {
      float o = b2[l];
#pragma unroll
      for (int jj = 0; jj < 16; ++jj) o += hid[sub][jj] * w2[jj * 4 + l];
      rlb[r * 4 + l] = o;
    }
  } else {
    // dist-bias lookup table: tab[i] = MLP3(MLP2(MLP1(rbf(i/512))))
    int i = (b - BUILD_BLKS - PROJ_BLKS - RLB_BLKS) * 256 + threadIdx.x;
    if (i < TABN) {
      float d = (float)i * (1.0f / TINV);
      float rb[16], h1[16], h2[16];
      const float step = 20.0f / 15.0f;
      const float inv_sigma = 1.0f / 1.25f;
#pragma unroll
      for (int jj = 0; jj < 16; ++jj) {
        float t = (d - jj * step) * inv_sigma;
        rb[jj] = __expf(-t * t);
      }
#pragma unroll
      for (int k = 0; k < 16; ++k) {
        float acc = rb1[k];
#pragma unroll
        for (int jj = 0; jj < 16; ++jj) acc += rb[jj] * rw1[jj * 16 + k];
        h1[k] = fmaxf(acc, 0.f);
      }
#pragma unroll
      for (int k = 0; k < 16; ++k) {
        float acc = rb2[k];
#pragma unroll
        for (int jj = 0; jj < 16; ++jj) acc += h1[jj] * rw2[jj * 16 + k];
        h2[k] = fmaxf(acc, 0.f);
      }
      f32x4 o;
#pragma unroll
      for (int h = 0; h < NH; ++h) {
        float acc = rb3[h];
#pragma unroll
        for (int jj = 0; jj < 16; ++jj) acc += h2[jj] * rw3[jj * 4 + h];
        o[h] = acc;
      }
      tab[i] = o;
    }
  }
}

// ---- per-edge R (1 wave/atom, 2 slots/lane) + per-atom softmax m,s --------
__global__ __launch_bounds__(256) void k_edgeR(
    const int* __restrict__ cnt_src, const unsigned* __restrict__ pay,
    const float* __restrict__ coords, const float* __restrict__ Qa,
    const float* __restrict__ Ka, const float* __restrict__ rlb,
    const f32x4* __restrict__ tab, float* __restrict__ R_slab,
    f32x4* __restrict__ msm, f32x4* __restrict__ mss) {
  int l = threadIdx.x & 63;
  int a = blockIdx.x * 4 + (threadIdx.x >> 6);
  int n = cnt_src[a];
  if (n > MAXS) n = MAXS;
  size_t base = (size_t)a * MAXS;
  float ax = coords[a * 3 + 0], ay = coords[a * 3 + 1], az = coords[a * 3 + 2];
  const float4* qp = (const float4*)(Qa + (size_t)a * 64);
  bool a0 = l < n, a1 = l + 64 < n;
  f32x4 R0, R1;
#pragma unroll
  for (int sl = 0; sl < 2; ++sl) {
    bool act = sl ? a1 : a0;
    f32x4 Rv = {-3.0e38f, -3.0e38f, -3.0e38f, -3.0e38f};
    if (act) {
      int s = l + sl * 64;
      unsigned pr = pay[base + s];
      int dst = (int)(pr & 0xFFFFu);
      int re = (int)(pr >> 16);
      float vx = coords[dst * 3 + 0] - ax + 1e-8f;
      float vy = coords[dst * 3 + 1] - ay + 1e-8f;
      float vz = coords[dst * 3 + 2] - az + 1e-8f;
      float d = sqrtf(vx * vx + vy * vy + vz * vz);
      float x = d * TINV;
      int i = (int)x;
      if (i > TABN - 2) i = TABN - 2;
      float fr = x - (float)i;
      f32x4 t0 = tab[i], t1 = tab[i + 1];
      f32x4 adb = t0 + (t1 - t0) * fr;
      const float4* kp = (const float4*)(Ka + (size_t)dst * 64);
      float4 rlb4 = *(const float4*)(rlb + re * 4);
      const float* rlbp = (const float*)&rlb4;
#pragma unroll
      for (int h = 0; h < NH; ++h) {
        float dot = 0.f;
#pragma unroll
        for (int v4 = 0; v4 < 4; ++v4) {
          float4 q4 = qp[h * 4 + v4];
          float4 k4 = kp[h * 4 + v4];
          dot += q4.x * k4.x + q4.y * k4.y + q4.z * k4.z + q4.w * k4.w;
        }
        Rv[h] = dot * 0.25f + rlbp[h] + adb[h];
      }
      __builtin_nontemporal_store(Rv, (f32x4*)(R_slab + (base + s) * 4));
    }
    if (sl) R1 = Rv; else R0 = Rv;
  }
  // per-atom, per-head max (pure shfl, wave = atom)
  f32x4 mx;
#pragma unroll
  for (int h = 0; h < NH; ++h) mx[h] = fmaxf(R0[h], R1[h]);
#pragma unroll
  for (int off = 1; off < 64; off <<= 1) {
#pragma unroll
    for (int h = 0; h < NH; ++h) mx[h] = fmaxf(mx[h], __shfl_xor(mx[h], off));
  }
  // per-atom, per-head exp-sum
  f32x4 ex;
#pragma unroll
  for (int h = 0; h < NH; ++h)
    ex[h] = (a0 ? __expf(R0[h] - mx[h]) : 0.f) +
            (a1 ? __expf(R1[h] - mx[h]) : 0.f);
#pragma unroll
  for (int off = 1; off < 64; off <<= 1) {
#pragma unroll
    for (int h = 0; h < NH; ++h) ex[h] += __shfl_xor(ex[h], off);
  }
  if (l == 0) {
    msm[a] = mx;
    mss[a] = ex;
  }
}

// ---- per-re sums via LDS-replicated accumulators, 256 blocks --------------
__global__ __launch_bounds__(1024) void k_re2(
    const int* __restrict__ cnt_src, const unsigned* __restrict__ pay,
    const float* __restrict__ R_slab, int* __restrict__ cntg,
    float* __restrict__ br_g) {
  __shared__ __align__(16) unsigned char smraw[64000];
  int* scnt = (int*)smraw;
  float* sbr = (float*)smraw;
  int tid = threadIdx.x;
  int bid = blockIdx.x;
  int wv = tid >> 6, lane = tid & 63;
  int gw = bid * 16 + wv;  // global wave id
  for (int j = tid; j < E_RES; j += 1024) scnt[j] = 0;
  __syncthreads();
  for (int a = gw; a < N_ATOM; a += NBRE * 16) {
    int n = cnt_src[a];
    if (n > MAXS) n = MAXS;
    size_t base = (size_t)a * MAXS;
    for (int i = lane; i < n; i += 64) {
      int re = (int)(pay[base + i] >> 16);
      atomicAdd(&scnt[re], 1);
    }
  }
  __syncthreads();
  for (int j = tid; j < E_RES; j += 1024) cntg[bid * E_RES + j] = scnt[j];
  __syncthreads();
  for (int j = tid; j < E_RES * 4; j += 1024) sbr[j] = 0.f;
  __syncthreads();
  for (int a = gw; a < N_ATOM; a += NBRE * 16) {
    int n = cnt_src[a];
    if (n > MAXS) n = MAXS;
    size_t base = (size_t)a * MAXS;
    for (int i = lane; i < n; i += 64) {
      int re = (int)(pay[base + i] >> 16);
      f32x4 r = *(const f32x4*)(R_slab + (base + i) * 4);
      atomicAdd(&sbr[re * 4 + 0], r[0]);
      atomicAdd(&sbr[re * 4 + 1], r[1]);
      atomicAdd(&sbr[re * 4 + 2], r[2]);
      atomicAdd(&sbr[re * 4 + 3], r[3]);
    }
  }
  __syncthreads();
  for (int j = tid; j < E_RES * 4; j += 1024)
    br_g[(size_t)bid * E_RES * 4 + j] = sbr[j];
}

// ---- reduce the 256 copies -> block_r (already divided by count) ----------
__global__ __launch_bounds__(256) void k_red(const float* __restrict__ br_g,
                                             const int* __restrict__ cntg,
                                             float* __restrict__ block_r) {
  int t = blockIdx.x * blockDim.x + threadIdx.x;
  if (t >= E_RES * 4) return;
  int r = t >> 2;
  float s = 0.f;
  int c = 0;
  for (int b = 0; b < NBRE; ++b) {
    s += br_g[(size_t)b * E_RES * 4 + t];
    c += cntg[b * E_RES + r];
  }
  block_r[t] = s / fmaxf((float)c, 1.0f);
}

// ---- residue softmax (max, denom, beta) fully in LDS, single block --------
__global__ __launch_bounds__(1024) void k_br23(
    const float* __restrict__ block_r, const int* __restrict__ rei,
    float* __restrict__ beta) {
  __shared__ unsigned resm[N_RES * 4];
  __shared__ float ress[N_RES * 4];
  int tid = threadIdx.x;
  for (int j = tid; j < N_RES * 4; j += 1024) { resm[j] = 0u; ress[j] = 0.f; }
  __syncthreads();
  float brv[4][4];
  int r1v[4];
  for (int k = 0; k < 4; ++k) {
    int r = tid + k * 1024;
    if (r < E_RES) {
      r1v[k] = rei[E_RES + r];
#pragma unroll
      for (int h = 0; h < 4; ++h) {
        brv[k][h] = block_r[r * 4 + h];
        atomicMax(&resm[r1v[k] * 4 + h], enc_f(brv[k][h]));
      }
    }
  }
  __syncthreads();
  for (int k = 0; k < 4; ++k) {
    int r = tid + k * 1024;
    if (r < E_RES) {
#pragma unroll
      for (int h = 0; h < 4; ++h)
        atomicAdd(&ress[r1v[k] * 4 + h],
                  __expf(brv[k][h] - dec_f(resm[r1v[k] * 4 + h])));
    }
  }
  __syncthreads();
  for (int k = 0; k < 4; ++k) {
    int r = tid + k * 1024;
    if (r < E_RES) {
#pragma unroll
      for (int h = 0; h < 4; ++h)
        beta[r * 4 + h] = __expf(brv[k][h] - dec_f(resm[r1v[k] * 4 + h])) /
                          (ress[r1v[k] * 4 + h] + 1e-16f);
    }
  }
}

// ---- per src atom: single-pass weighted V + fused output GEMM -------------
__global__ __launch_bounds__(256) void k_src(
    const int* __restrict__ cnt_src, const unsigned* __restrict__ pay,
    const float* __restrict__ R_slab, const float* __restrict__ beta,
    const float* __restrict__ Va, const f32x4* __restrict__ msm,
    const f32x4* __restrict__ mss, const float* __restrict__ wo,
    const float* __restrict__ bo, float* __restrict__ out) {
  __shared__ float sau[4][64];
  int wv = threadIdx.x >> 6, l = threadIdx.x & 63;
  int wid = blockIdx.x * 4 + wv;  // 3500 blocks * 4 waves = 14000 atoms exact
  int n = cnt_src[wid];
  if (n > MAXS) n = MAXS;
  int h = l >> 4;
  size_t rbase = (size_t)wid * MAXS;
  f32x4 m4 = msm[wid], s4 = mss[wid];
  float mh = m4[h];
  float sden = s4[h] + 1e-16f;
  float acc = 0.f;
#pragma unroll 2
  for (int i = 0; i < n; ++i) {
    unsigned pr = pay[rbase + i];
    int dst = (int)(pr & 0xFFFFu);
    int re = (int)(pr >> 16);
    float rv = R_slab[(rbase + i) * 4 + h];
    float bt = beta[re * 4 + h];
    float v = Va[(size_t)dst * 64 + l];
    acc += __expf(rv - mh) * bt * v;
  }
  sau[wv][l] = acc / sden;
  __syncthreads();
  // out[wid] = au . wo + bo  (64x16 GEMV in-wave)
  int p = l >> 4, c = l & 15;
  float part = 0.f;
#pragma unroll
  for (int jj = 0; jj < 16; ++jj)
    part += sau[wv][p * 16 + jj] * wo[(p * 16 + jj) * 16 + c];
  part += __shfl_down(part, 32);
  part += __shfl_down(part, 16);
  if (l < 16) out[wid * 16 + c] = part + bo[c];
}

extern "C" void kernel_launch(void* const* d_in, const int* in_sizes, int n_in,
                              void* d_out, int out_size, void* d_ws,
                              size_t ws_size, hipStream_t stream) {
  const float* nf   = (const float*)d_in[0];
  const float* ref_ = (const float*)d_in[1];
  const int*   rei  = (const int*)d_in[2];
  const float* af   = (const float*)d_in[3];
  const float* co   = (const float*)d_in[4];
  const int*   cei  = (const int*)d_in[5];
  const int*   aer  = (const int*)d_in[6];
  const float* rw1  = (const float*)d_in[7];
  const float* rb1  = (const float*)d_in[8];
  const float* rw2  = (const float*)d_in[9];
  const float* rb2  = (const float*)d_in[10];
  const float* rw3  = (const float*)d_in[11];
  const float* rb3  = (const float*)d_in[12];
  const float* w1   = (const float*)d_in[13];
  const float* b1   = (const float*)d_in[14];
  const float* w2   = (const float*)d_in[15];
  const float* b2   = (const float*)d_in[16];
  const float* wq   = (const float*)d_in[17];
  const float* bq   = (const float*)d_in[18];
  const float* wkv  = (const float*)d_in[19];
  const float* bkv  = (const float*)d_in[20];
  const float* wo   = (const float*)d_in[21];
  const float* bo   = (const float*)d_in[22];
  float* out = (float*)d_out;

  float* ws = (float*)d_ws;
  float*    Qa      = ws;                            //  896000
  float*    Ka      = Qa + 896000;                   //  896000
  float*    Va      = Ka + 896000;                   //  896000
  float*    rlb     = Va + 896000;                   //   16000
  float*    R_slab  = rlb + 16000;                   // 7168000
  unsigned* pay     = (unsigned*)(R_slab + 7168000); // 1792000
  float*    br_g    = (float*)(pay + 1792000);       // 4096000 (256*16000)
  int*      cntg    = (int*)(br_g + 4096000);        // 1024000 (256*4000)
  int*      cnt_src = cntg + 1024000;                //   14000 [zero]
  float*    block_r = (float*)(cnt_src + 14000);     //   16000
  f32x4*    tab     = (f32x4*)(block_r + 16000);     //   65540 floats
  f32x4*    msm     = (f32x4*)((float*)tab + 65544); //   56000 floats
  f32x4*    mss     = (f32x4*)((float*)msm + 56000); //   56000 floats
  // overlays (dead after k_edgeR):
  float*    beta    = Ka + 16000;                    //   16000

  hipMemsetAsync((void*)cnt_src, 0, 14000 * 4, stream);

  kA<<<BUILD_BLKS + PROJ_BLKS + RLB_BLKS + TAB_BLKS, 256, 0, stream>>>(
      cei, aer, cnt_src, pay, af, wq, bq, wkv, bkv, Qa, Ka, Va, ref_, nf, rei,
      w1, b1, w2, b2, rlb, rw1, rb1, rw2, rb2, rw3, rb3, tab);
  k_edgeR<<<N_ATOM / 4, 256, 0, stream>>>(cnt_src, pay, co, Qa, Ka, rlb, tab,
                                          R_slab, msm, mss);
  k_re2<<<NBRE, 1024, 0, stream>>>(cnt_src, pay, R_slab, cntg, br_g);
  k_red<<<(E_RES * 4 + 255) / 256, 256, 0, stream>>>(br_g, cntg, block_r);
  k_br23<<<1, 1024, 0, stream>>>(block_r, rei, beta);
  k_src<<<N_ATOM / 4, 256, 0, stream>>>(cnt_src, pay, R_slab, beta, Va, msm,
                                        mss, wo, bo, out);
}

// Round 11
// 247.560 us; speedup vs baseline: 1.6850x; 1.0196x over previous
//
#include <hip/hip_runtime.h>

#define NH 4
#define N_RES 1000
#define E_RES 4000
#define N_ATOM 14000
#define E_ATOM 784000
#define MAXS 128    // src-slab slots/atom (Poisson λ=56, 128 is ~9.6σ)
#define NBRE 256    // blocks for k_re2 (1 per CU)
#define TABN 16385  // dist-bias table entries over [0,32], Δ=1/512
#define TINV 512.0f
#define NHB 256     // histogram blocks (counting-sort build)
#define EPB 3063    // edges per histogram block (256*3063 >= E_ATOM)

#define HIST_BLKS NHB
#define PROJ_BLKS ((N_ATOM * 192 + 255) / 256)  // 10500
#define RLB_BLKS (E_RES / 4)                    // 1000
#define TAB_BLKS ((TABN + 255) / 256)           // 65

typedef float f32x4 __attribute__((ext_vector_type(4)));

__device__ __forceinline__ unsigned enc_f(float f) {
  unsigned u = __float_as_uint(f);
  return (u & 0x80000000u) ? ~u : (u | 0x80000000u);
}
__device__ __forceinline__ float dec_f(unsigned e) {
  unsigned u = (e & 0x80000000u) ? (e & 0x7FFFFFFFu) : ~e;
  return __uint_as_float(u);
}

// ---- fused: LDS src-histogram + Q/K/V proj + res_level_bias + dist table --
__global__ __launch_bounds__(256) void kA(
    const int* __restrict__ cei, int* __restrict__ ghist,
    const float* __restrict__ af, const float* __restrict__ wq,
    const float* __restrict__ bq, const float* __restrict__ wkv,
    const float* __restrict__ bkv, float* __restrict__ Qa,
    float* __restrict__ Ka, float* __restrict__ Va,
    const float* __restrict__ ref_, const float* __restrict__ nf,
    const int* __restrict__ rei, const float* __restrict__ w1,
    const float* __restrict__ b1, const float* __restrict__ w2,
    const float* __restrict__ b2, float* __restrict__ rlb,
    const float* __restrict__ rw1, const float* __restrict__ rb1,
    const float* __restrict__ rw2, const float* __restrict__ rb2,
    const float* __restrict__ rw3, const float* __restrict__ rb3,
    f32x4* __restrict__ tab) {
  __shared__ unsigned lhist[N_ATOM / 2];  // packed 2x u16, 28KB
  int b = blockIdx.x;
  if (b < HIST_BLKS) {
    int t = threadIdx.x;
    for (int j = t; j < N_ATOM / 2; j += 256) lhist[j] = 0u;
    __syncthreads();
    int e0 = b * EPB;
    int e1 = e0 + EPB;
    if (e1 > E_ATOM) e1 = E_ATOM;
    for (int e = e0 + t; e < e1; e += 256) {
      int src = cei[E_ATOM + e];
      atomicAdd(&lhist[src >> 1], (src & 1) ? 65536u : 1u);
    }
    __syncthreads();
    int2* gh = (int2*)(ghist + (size_t)b * N_ATOM);
    for (int j = t; j < N_ATOM / 2; j += 256) {
      unsigned v = lhist[j];
      gh[j] = make_int2((int)(v & 0xFFFFu), (int)(v >> 16));
    }
  } else if (b < HIST_BLKS + PROJ_BLKS) {
    int tid = (b - HIST_BLKS) * 256 + threadIdx.x;
    if (tid < N_ATOM * 192) {
      int a = tid / 192, j = tid % 192;
      const float* row = af + a * 16;
      if (j < 64) {
        float acc = bq[j];
#pragma unroll
        for (int i = 0; i < 16; ++i) acc += row[i] * wq[i * 64 + j];
        Qa[a * 64 + j] = acc;
      } else if (j < 128) {
        int jj = j - 64;
        int col = ((jj >> 4) << 5) + (jj & 15);  // head h, k half
        float acc = bkv[col];
#pragma unroll
        for (int i = 0; i < 16; ++i) acc += row[i] * wkv[i * 128 + col];
        Ka[a * 64 + jj] = acc;
      } else {
        int jj = j - 128;
        int col = ((jj >> 4) << 5) + 16 + (jj & 15);  // head h, v half
        float acc = bkv[col];
#pragma unroll
        for (int i = 0; i < 16; ++i) acc += row[i] * wkv[i * 128 + col];
        Va[a * 64 + jj] = acc;
      }
    }
  } else if (b < HIST_BLKS + PROJ_BLKS + RLB_BLKS) {
    __shared__ float hid[4][16];
    int sub = threadIdx.x >> 6, l = threadIdx.x & 63;
    int r = (b - HIST_BLKS - PROJ_BLKS) * 4 + sub;
    int r0 = rei[r], r1 = rei[E_RES + r];
    int j = l >> 2, pq = l & 3;
    float acc = 0.f;
    for (int i = pq; i < 320; i += 4) {
      float cc;
      if (i < 64) cc = ref_[r * 64 + i];
      else if (i < 192) cc = nf[r0 * 128 + (i - 64)];
      else cc = nf[r1 * 128 + (i - 192)];
      acc += cc * w1[i * 16 + j];
    }
    acc += __shfl_xor(acc, 1);
    acc += __shfl_xor(acc, 2);
    if (pq == 0) hid[sub][j] = fmaxf(acc + b1[j], 0.f);
    __syncthreads();
    if (l < 4) {
      float o = b2[l];
#pragma unroll
      for (int jj = 0; jj < 16; ++jj) o += hid[sub][jj] * w2[jj * 4 + l];
      rlb[r * 4 + l] = o;
    }
  } else {
    // dist-bias lookup table: tab[i] = MLP3(MLP2(MLP1(rbf(i/512))))
    int i = (b - HIST_BLKS - PROJ_BLKS - RLB_BLKS) * 256 + threadIdx.x;
    if (i < TABN) {
      float d = (float)i * (1.0f / TINV);
      float rb[16], h1[16], h2[16];
      const float step = 20.0f / 15.0f;
      const float inv_sigma = 1.0f / 1.25f;
#pragma unroll
      for (int jj = 0; jj < 16; ++jj) {
        float t = (d - jj * step) * inv_sigma;
        rb[jj] = __expf(-t * t);
      }
#pragma unroll
      for (int k = 0; k < 16; ++k) {
        float acc = rb1[k];
#pragma unroll
        for (int jj = 0; jj < 16; ++jj) acc += rb[jj] * rw1[jj * 16 + k];
        h1[k] = fmaxf(acc, 0.f);
      }
#pragma unroll
      for (int k = 0; k < 16; ++k) {
        float acc = rb2[k];
#pragma unroll
        for (int jj = 0; jj < 16; ++jj) acc += h1[jj] * rw2[jj * 16 + k];
        h2[k] = fmaxf(acc, 0.f);
      }
      f32x4 o;
#pragma unroll
      for (int h = 0; h < NH; ++h) {
        float acc = rb3[h];
#pragma unroll
        for (int jj = 0; jj < 16; ++jj) acc += h2[jj] * rw3[jj * 4 + h];
        o[h] = acc;
      }
      tab[i] = o;
    }
  }
}

// ---- per-src exclusive scan over hist blocks (no atomics) -----------------
__global__ __launch_bounds__(256) void k_ofs(const int* __restrict__ ghist,
                                             int* __restrict__ ofs,
                                             int* __restrict__ cnt_src) {
  int s = blockIdx.x * blockDim.x + threadIdx.x;
  if (s >= N_ATOM) return;
  int run = 0;
  for (int b = 0; b < NHB; ++b) {
    int v = ghist[(size_t)b * N_ATOM + s];
    ofs[(size_t)b * N_ATOM + s] = run;
    run += v;
  }
  cnt_src[s] = (run > MAXS) ? MAXS : run;
}

// ---- scatter into slab: slot = LDS base+rank, plain stores ----------------
__global__ __launch_bounds__(256) void k_scat(
    const int* __restrict__ cei, const int* __restrict__ aer,
    const int* __restrict__ ofs, unsigned* __restrict__ pay) {
  __shared__ int lbase[N_ATOM];  // 56KB: this block's exclusive bases
  int b = blockIdx.x, t = threadIdx.x;
  const int* orow = ofs + (size_t)b * N_ATOM;
  for (int j = t; j < N_ATOM; j += 256) lbase[j] = orow[j];
  __syncthreads();
  int e0 = b * EPB;
  int e1 = e0 + EPB;
  if (e1 > E_ATOM) e1 = E_ATOM;
  for (int e = e0 + t; e < e1; e += 256) {
    int src = cei[E_ATOM + e];
    int dst = cei[e];
    int re = aer[e];
    int slot = atomicAdd(&lbase[src], 1);
    if (slot < MAXS)
      pay[(size_t)src * MAXS + slot] = (unsigned)dst | ((unsigned)re << 16);
  }
}

// ---- per-edge R (1 wave/atom, 2 slots/lane) + per-atom softmax m,s --------
__global__ __launch_bounds__(256) void k_edgeR(
    const int* __restrict__ cnt_src, const unsigned* __restrict__ pay,
    const float* __restrict__ coords, const float* __restrict__ Qa,
    const float* __restrict__ Ka, const float* __restrict__ rlb,
    const f32x4* __restrict__ tab, float* __restrict__ R_slab,
    f32x4* __restrict__ msm, f32x4* __restrict__ mss) {
  int l = threadIdx.x & 63;
  int a = blockIdx.x * 4 + (threadIdx.x >> 6);
  int n = cnt_src[a];
  if (n > MAXS) n = MAXS;
  size_t base = (size_t)a * MAXS;
  float ax = coords[a * 3 + 0], ay = coords[a * 3 + 1], az = coords[a * 3 + 2];
  const float4* qp = (const float4*)(Qa + (size_t)a * 64);
  bool a0 = l < n, a1 = l + 64 < n;
  f32x4 R0, R1;
#pragma unroll
  for (int sl = 0; sl < 2; ++sl) {
    bool act = sl ? a1 : a0;
    f32x4 Rv = {-3.0e38f, -3.0e38f, -3.0e38f, -3.0e38f};
    if (act) {
      int s = l + sl * 64;
      unsigned pr = pay[base + s];
      int dst = (int)(pr & 0xFFFFu);
      int re = (int)(pr >> 16);
      float vx = coords[dst * 3 + 0] - ax + 1e-8f;
      float vy = coords[dst * 3 + 1] - ay + 1e-8f;
      float vz = coords[dst * 3 + 2] - az + 1e-8f;
      float d = sqrtf(vx * vx + vy * vy + vz * vz);
      float x = d * TINV;
      int i = (int)x;
      if (i > TABN - 2) i = TABN - 2;
      float fr = x - (float)i;
      f32x4 t0 = tab[i], t1 = tab[i + 1];
      f32x4 adb = t0 + (t1 - t0) * fr;
      const float4* kp = (const float4*)(Ka + (size_t)dst * 64);
      float4 rlb4 = *(const float4*)(rlb + re * 4);
      const float* rlbp = (const float*)&rlb4;
#pragma unroll
      for (int h = 0; h < NH; ++h) {
        float dot = 0.f;
#pragma unroll
        for (int v4 = 0; v4 < 4; ++v4) {
          float4 q4 = qp[h * 4 + v4];
          float4 k4 = kp[h * 4 + v4];
          dot += q4.x * k4.x + q4.y * k4.y + q4.z * k4.z + q4.w * k4.w;
        }
        Rv[h] = dot * 0.25f + rlbp[h] + adb[h];
      }
      __builtin_nontemporal_store(Rv, (f32x4*)(R_slab + (base + s) * 4));
    }
    if (sl) R1 = Rv; else R0 = Rv;
  }
  f32x4 mx;
#pragma unroll
  for (int h = 0; h < NH; ++h) mx[h] = fmaxf(R0[h], R1[h]);
#pragma unroll
  for (int off = 1; off < 64; off <<= 1) {
#pragma unroll
    for (int h = 0; h < NH; ++h) mx[h] = fmaxf(mx[h], __shfl_xor(mx[h], off));
  }
  f32x4 ex;
#pragma unroll
  for (int h = 0; h < NH; ++h)
    ex[h] = (a0 ? __expf(R0[h] - mx[h]) : 0.f) +
            (a1 ? __expf(R1[h] - mx[h]) : 0.f);
#pragma unroll
  for (int off = 1; off < 64; off <<= 1) {
#pragma unroll
    for (int h = 0; h < NH; ++h) ex[h] += __shfl_xor(ex[h], off);
  }
  if (l == 0) {
    msm[a] = mx;
    mss[a] = ex;
  }
}

// ---- per-re sums via LDS-replicated accumulators, 256 blocks --------------
__global__ __launch_bounds__(1024) void k_re2(
    const int* __restrict__ cnt_src, const unsigned* __restrict__ pay,
    const float* __restrict__ R_slab, int* __restrict__ cntg,
    float* __restrict__ br_g) {
  __shared__ __align__(16) unsigned char smraw[64000];
  int* scnt = (int*)smraw;
  float* sbr = (float*)smraw;
  int tid = threadIdx.x;
  int bid = blockIdx.x;
  int wv = tid >> 6, lane = tid & 63;
  int gw = bid * 16 + wv;  // global wave id
  for (int j = tid; j < E_RES; j += 1024) scnt[j] = 0;
  __syncthreads();
  for (int a = gw; a < N_ATOM; a += NBRE * 16) {
    int n = cnt_src[a];
    if (n > MAXS) n = MAXS;
    size_t base = (size_t)a * MAXS;
    for (int i = lane; i < n; i += 64) {
      int re = (int)(pay[base + i] >> 16);
      atomicAdd(&scnt[re], 1);
    }
  }
  __syncthreads();
  for (int j = tid; j < E_RES; j += 1024) cntg[bid * E_RES + j] = scnt[j];
  __syncthreads();
  for (int j = tid; j < E_RES * 4; j += 1024) sbr[j] = 0.f;
  __syncthreads();
  for (int a = gw; a < N_ATOM; a += NBRE * 16) {
    int n = cnt_src[a];
    if (n > MAXS) n = MAXS;
    size_t base = (size_t)a * MAXS;
    for (int i = lane; i < n; i += 64) {
      int re = (int)(pay[base + i] >> 16);
      f32x4 r = *(const f32x4*)(R_slab + (base + i) * 4);
      atomicAdd(&sbr[re * 4 + 0], r[0]);
      atomicAdd(&sbr[re * 4 + 1], r[1]);
      atomicAdd(&sbr[re * 4 + 2], r[2]);
      atomicAdd(&sbr[re * 4 + 3], r[3]);
    }
  }
  __syncthreads();
  for (int j = tid; j < E_RES * 4; j += 1024)
    br_g[(size_t)bid * E_RES * 4 + j] = sbr[j];
}

// ---- reduce the 256 copies -> block_r (already divided by count) ----------
__global__ __launch_bounds__(256) void k_red(const float* __restrict__ br_g,
                                             const int* __restrict__ cntg,
                                             float* __restrict__ block_r) {
  int t = blockIdx.x * blockDim.x + threadIdx.x;
  if (t >= E_RES * 4) return;
  int r = t >> 2;
  float s = 0.f;
  int c = 0;
  for (int b = 0; b < NBRE; ++b) {
    s += br_g[(size_t)b * E_RES * 4 + t];
    c += cntg[b * E_RES + r];
  }
  block_r[t] = s / fmaxf((float)c, 1.0f);
}

// ---- residue softmax (max, denom, beta) fully in LDS, single block --------
__global__ __launch_bounds__(1024) void k_br23(
    const float* __restrict__ block_r, const int* __restrict__ rei,
    float* __restrict__ beta) {
  __shared__ unsigned resm[N_RES * 4];
  __shared__ float ress[N_RES * 4];
  int tid = threadIdx.x;
  for (int j = tid; j < N_RES * 4; j += 1024) { resm[j] = 0u; ress[j] = 0.f; }
  __syncthreads();
  float brv[4][4];
  int r1v[4];
  for (int k = 0; k < 4; ++k) {
    int r = tid + k * 1024;
    if (r < E_RES) {
      r1v[k] = rei[E_RES + r];
#pragma unroll
      for (int h = 0; h < 4; ++h) {
        brv[k][h] = block_r[r * 4 + h];
        atomicMax(&resm[r1v[k] * 4 + h], enc_f(brv[k][h]));
      }
    }
  }
  __syncthreads();
  for (int k = 0; k < 4; ++k) {
    int r = tid + k * 1024;
    if (r < E_RES) {
#pragma unroll
      for (int h = 0; h < 4; ++h)
        atomicAdd(&ress[r1v[k] * 4 + h],
                  __expf(brv[k][h] - dec_f(resm[r1v[k] * 4 + h])));
    }
  }
  __syncthreads();
  for (int k = 0; k < 4; ++k) {
    int r = tid + k * 1024;
    if (r < E_RES) {
#pragma unroll
      for (int h = 0; h < 4; ++h)
        beta[r * 4 + h] = __expf(brv[k][h] - dec_f(resm[r1v[k] * 4 + h])) /
                          (ress[r1v[k] * 4 + h] + 1e-16f);
    }
  }
}

// ---- per src atom: single-pass weighted V + fused output GEMM -------------
__global__ __launch_bounds__(256) void k_src(
    const int* __restrict__ cnt_src, const unsigned* __restrict__ pay,
    const float* __restrict__ R_slab, const float* __restrict__ beta,
    const float* __restrict__ Va, const f32x4* __restrict__ msm,
    const f32x4* __restrict__ mss, const float* __restrict__ wo,
    const float* __restrict__ bo, float* __restrict__ out) {
  __shared__ float sau[4][64];
  int wv = threadIdx.x >> 6, l = threadIdx.x & 63;
  int wid = blockIdx.x * 4 + wv;  // 3500 blocks * 4 waves = 14000 atoms exact
  int n = cnt_src[wid];
  if (n > MAXS) n = MAXS;
  int h = l >> 4;
  size_t rbase = (size_t)wid * MAXS;
  f32x4 m4 = msm[wid], s4 = mss[wid];
  float mh = m4[h];
  float sden = s4[h] + 1e-16f;
  float acc = 0.f;
#pragma unroll 2
  for (int i = 0; i < n; ++i) {
    unsigned pr = pay[rbase + i];
    int dst = (int)(pr & 0xFFFFu);
    int re = (int)(pr >> 16);
    float rv = R_slab[(rbase + i) * 4 + h];
    float bt = beta[re * 4 + h];
    float v = Va[(size_t)dst * 64 + l];
    acc += __expf(rv - mh) * bt * v;
  }
  sau[wv][l] = acc / sden;
  __syncthreads();
  // out[wid] = au . wo + bo  (64x16 GEMV in-wave)
  int p = l >> 4, c = l & 15;
  float part = 0.f;
#pragma unroll
  for (int jj = 0; jj < 16; ++jj)
    part += sau[wv][p * 16 + jj] * wo[(p * 16 + jj) * 16 + c];
  part += __shfl_down(part, 32);
  part += __shfl_down(part, 16);
  if (l < 16) out[wid * 16 + c] = part + bo[c];
}

extern "C" void kernel_launch(void* const* d_in, const int* in_sizes, int n_in,
                              void* d_out, int out_size, void* d_ws,
                              size_t ws_size, hipStream_t stream) {
  const float* nf   = (const float*)d_in[0];
  const float* ref_ = (const float*)d_in[1];
  const int*   rei  = (const int*)d_in[2];
  const float* af   = (const float*)d_in[3];
  const float* co   = (const float*)d_in[4];
  const int*   cei  = (const int*)d_in[5];
  const int*   aer  = (const int*)d_in[6];
  const float* rw1  = (const float*)d_in[7];
  const float* rb1  = (const float*)d_in[8];
  const float* rw2  = (const float*)d_in[9];
  const float* rb2  = (const float*)d_in[10];
  const float* rw3  = (const float*)d_in[11];
  const float* rb3  = (const float*)d_in[12];
  const float* w1   = (const float*)d_in[13];
  const float* b1   = (const float*)d_in[14];
  const float* w2   = (const float*)d_in[15];
  const float* b2   = (const float*)d_in[16];
  const float* wq   = (const float*)d_in[17];
  const float* bq   = (const float*)d_in[18];
  const float* wkv  = (const float*)d_in[19];
  const float* bkv  = (const float*)d_in[20];
  const float* wo   = (const float*)d_in[21];
  const float* bo   = (const float*)d_in[22];
  float* out = (float*)d_out;

  float* ws = (float*)d_ws;
  float*    Qa      = ws;                            //  896000
  float*    Ka      = Qa + 896000;                   //  896000
  float*    Va      = Ka + 896000;                   //  896000
  float*    rlb     = Va + 896000;                   //   16000
  float*    R_slab  = rlb + 16000;                   // 7168000
  unsigned* pay     = (unsigned*)(R_slab + 7168000); // 1792000
  float*    br_g    = (float*)(pay + 1792000);       // 4096000 (256*16000)
  int*      cntg    = (int*)(br_g + 4096000);        // 1024000 (256*4000)
  int*      cnt_src = cntg + 1024000;                //   14000
  float*    block_r = (float*)(cnt_src + 14000);     //   16000
  f32x4*    tab     = (f32x4*)(block_r + 16000);     //   65540 floats
  f32x4*    msm     = (f32x4*)((float*)tab + 65544); //   56000 floats
  f32x4*    mss     = (f32x4*)((float*)msm + 56000); //   56000 floats
  // overlays:
  int*      ghist   = (int*)br_g;    // 3584000 ints, dead before k_re2 writes
  int*      ofs     = (int*)R_slab;  // 3584000 ints, dead before k_edgeR writes
  float*    beta    = Ka + 16000;    // dead region of Ka after k_edgeR

  kA<<<HIST_BLKS + PROJ_BLKS + RLB_BLKS + TAB_BLKS, 256, 0, stream>>>(
      cei, ghist, af, wq, bq, wkv, bkv, Qa, Ka, Va, ref_, nf, rei, w1, b1, w2,
      b2, rlb, rw1, rb1, rw2, rb2, rw3, rb3, tab);
  k_ofs<<<(N_ATOM + 255) / 256, 256, 0, stream>>>(ghist, ofs, cnt_src);
  k_scat<<<NHB, 256, 0, stream>>>(cei, aer, ofs, pay);
  k_edgeR<<<N_ATOM / 4, 256, 0, stream>>>(cnt_src, pay, co, Qa, Ka, rlb, tab,
                                          R_slab, msm, mss);
  k_re2<<<NBRE, 1024, 0, stream>>>(cnt_src, pay, R_slab, cntg, br_g);
  k_red<<<(E_RES * 4 + 255) / 256, 256, 0, stream>>>(br_g, cntg, block_r);
  k_br23<<<1, 1024, 0, stream>>>(block_r, rei, beta);
  k_src<<<N_ATOM / 4, 256, 0, stream>>>(cnt_src, pay, R_slab, beta, Va, msm,
                                        mss, wo, bo, out);
}

// Round 12
// 237.456 us; speedup vs baseline: 1.7567x; 1.0426x over previous
//
#include <hip/hip_runtime.h>

#define NH 4
#define N_RES 1000
#define E_RES 4000
#define N_ATOM 14000
#define E_ATOM 784000
#define MAXS 128    // src-slab slots/atom (Poisson λ=56, 128 is ~9.6σ)
#define NBRE 256    // blocks for k_re2
#define TABN 16385  // dist-bias table entries over [0,32], Δ=1/512
#define TINV 512.0f
#define NHB 256     // histogram blocks (counting-sort build)
#define EPB 3063    // edges per histogram block (256*3063 >= E_ATOM)

#define PROJ_BLKS ((N_ATOM * 192 + 255) / 256)  // 10500
#define RLB_BLKS (E_RES / 4)                    // 1000
#define TAB_BLKS ((TABN + 255) / 256)           // 65

typedef float f32x4 __attribute__((ext_vector_type(4)));

__device__ __forceinline__ unsigned enc_f(float f) {
  unsigned u = __float_as_uint(f);
  return (u & 0x80000000u) ? ~u : (u | 0x80000000u);
}
__device__ __forceinline__ float dec_f(unsigned e) {
  unsigned u = (e & 0x80000000u) ? (e & 0x7FFFFFFFu) : ~e;
  return __uint_as_float(u);
}

// ---- per-block src histogram (LDS, packed u16) ----------------------------
__global__ __launch_bounds__(256) void k_hist(const int* __restrict__ cei,
                                              unsigned* __restrict__ ghistP) {
  __shared__ unsigned lhist[N_ATOM / 2];  // packed 2x u16, 28KB
  int b = blockIdx.x, t = threadIdx.x;
  for (int j = t; j < N_ATOM / 2; j += 256) lhist[j] = 0u;
  __syncthreads();
  int e0 = b * EPB, e1 = e0 + EPB;
  if (e1 > E_ATOM) e1 = E_ATOM;
  for (int e = e0 + t; e < e1; e += 256) {
    int src = cei[E_ATOM + e];
    atomicAdd(&lhist[src >> 1], (src & 1) ? 65536u : 1u);
  }
  __syncthreads();
  unsigned* gh = ghistP + (size_t)b * (N_ATOM / 2);
  for (int j = t; j < N_ATOM / 2; j += 256) gh[j] = lhist[j];
}

// ---- fused: Q/K/V proj + res_level_bias + dist-bias table (tiny LDS) ------
__global__ __launch_bounds__(256) void kA2(
    const float* __restrict__ af, const float* __restrict__ wq,
    const float* __restrict__ bq, const float* __restrict__ wkv,
    const float* __restrict__ bkv, float* __restrict__ Qa,
    float* __restrict__ Ka, float* __restrict__ Va,
    const float* __restrict__ ref_, const float* __restrict__ nf,
    const int* __restrict__ rei, const float* __restrict__ w1,
    const float* __restrict__ b1, const float* __restrict__ w2,
    const float* __restrict__ b2, float* __restrict__ rlb,
    const float* __restrict__ rw1, const float* __restrict__ rb1,
    const float* __restrict__ rw2, const float* __restrict__ rb2,
    const float* __restrict__ rw3, const float* __restrict__ rb3,
    f32x4* __restrict__ tab) {
  __shared__ float hid[4][16];
  int b = blockIdx.x;
  if (b < PROJ_BLKS) {
    int tid = b * 256 + threadIdx.x;
    if (tid < N_ATOM * 192) {
      int a = tid / 192, j = tid % 192;
      const float* row = af + a * 16;
      if (j < 64) {
        float acc = bq[j];
#pragma unroll
        for (int i = 0; i < 16; ++i) acc += row[i] * wq[i * 64 + j];
        Qa[a * 64 + j] = acc;
      } else if (j < 128) {
        int jj = j - 64;
        int col = ((jj >> 4) << 5) + (jj & 15);  // head h, k half
        float acc = bkv[col];
#pragma unroll
        for (int i = 0; i < 16; ++i) acc += row[i] * wkv[i * 128 + col];
        Ka[a * 64 + jj] = acc;
      } else {
        int jj = j - 128;
        int col = ((jj >> 4) << 5) + 16 + (jj & 15);  // head h, v half
        float acc = bkv[col];
#pragma unroll
        for (int i = 0; i < 16; ++i) acc += row[i] * wkv[i * 128 + col];
        Va[a * 64 + jj] = acc;
      }
    }
  } else if (b < PROJ_BLKS + RLB_BLKS) {
    int sub = threadIdx.x >> 6, l = threadIdx.x & 63;
    int r = (b - PROJ_BLKS) * 4 + sub;
    int r0 = rei[r], r1 = rei[E_RES + r];
    int j = l >> 2, pq = l & 3;
    float acc = 0.f;
    for (int i = pq; i < 320; i += 4) {
      float cc;
      if (i < 64) cc = ref_[r * 64 + i];
      else if (i < 192) cc = nf[r0 * 128 + (i - 64)];
      else cc = nf[r1 * 128 + (i - 192)];
      acc += cc * w1[i * 16 + j];
    }
    acc += __shfl_xor(acc, 1);
    acc += __shfl_xor(acc, 2);
    if (pq == 0) hid[sub][j] = fmaxf(acc + b1[j], 0.f);
    __syncthreads();
    if (l < 4) {
      float o = b2[l];
#pragma unroll
      for (int jj = 0; jj < 16; ++jj) o += hid[sub][jj] * w2[jj * 4 + l];
      rlb[r * 4 + l] = o;
    }
  } else {
    int i = (b - PROJ_BLKS - RLB_BLKS) * 256 + threadIdx.x;
    if (i < TABN) {
      float d = (float)i * (1.0f / TINV);
      float rb[16], h1[16], h2[16];
      const float step = 20.0f / 15.0f;
      const float inv_sigma = 1.0f / 1.25f;
#pragma unroll
      for (int jj = 0; jj < 16; ++jj) {
        float t = (d - jj * step) * inv_sigma;
        rb[jj] = __expf(-t * t);
      }
#pragma unroll
      for (int k = 0; k < 16; ++k) {
        float acc = rb1[k];
#pragma unroll
        for (int jj = 0; jj < 16; ++jj) acc += rb[jj] * rw1[jj * 16 + k];
        h1[k] = fmaxf(acc, 0.f);
      }
#pragma unroll
      for (int k = 0; k < 16; ++k) {
        float acc = rb2[k];
#pragma unroll
        for (int jj = 0; jj < 16; ++jj) acc += h1[jj] * rw2[jj * 16 + k];
        h2[k] = fmaxf(acc, 0.f);
      }
      f32x4 o;
#pragma unroll
      for (int h = 0; h < NH; ++h) {
        float acc = rb3[h];
#pragma unroll
        for (int jj = 0; jj < 16; ++jj) acc += h2[jj] * rw3[jj * 4 + h];
        o[h] = acc;
      }
      tab[i] = o;
    }
  }
}

// ---- per-src exclusive scan over hist blocks (u16 in/out, no atomics) -----
__global__ __launch_bounds__(256) void k_ofs(const unsigned* __restrict__ ghistP,
                                             unsigned short* __restrict__ ofs16,
                                             int* __restrict__ cnt_src) {
  int s = blockIdx.x * blockDim.x + threadIdx.x;
  if (s >= N_ATOM) return;
  int half = s >> 1;
  unsigned sel = (s & 1) ? 16 : 0;
  int run = 0;
#pragma unroll 8
  for (int b = 0; b < NHB; ++b) {
    int v = (int)((ghistP[(size_t)b * (N_ATOM / 2) + half] >> sel) & 0xFFFFu);
    ofs16[(size_t)b * N_ATOM + s] = (unsigned short)run;
    run += v;
  }
  cnt_src[s] = (run > MAXS) ? MAXS : run;
}

// ---- scatter into slab: slot = LDS base+rank, plain stores ----------------
__global__ __launch_bounds__(256) void k_scat(
    const int* __restrict__ cei, const int* __restrict__ aer,
    const unsigned* __restrict__ ofs16P, unsigned* __restrict__ pay) {
  __shared__ int lbase[N_ATOM];  // 56KB: this block's exclusive bases
  int b = blockIdx.x, t = threadIdx.x;
  const unsigned* orow = ofs16P + (size_t)b * (N_ATOM / 2);
  for (int j = t; j < N_ATOM / 2; j += 256) {
    unsigned v = orow[j];
    lbase[2 * j] = (int)(v & 0xFFFFu);
    lbase[2 * j + 1] = (int)(v >> 16);
  }
  __syncthreads();
  int e0 = b * EPB, e1 = e0 + EPB;
  if (e1 > E_ATOM) e1 = E_ATOM;
  for (int e = e0 + t; e < e1; e += 256) {
    int src = cei[E_ATOM + e];
    int dst = cei[e];
    int re = aer[e];
    int slot = atomicAdd(&lbase[src], 1);
    if (slot < MAXS)
      pay[(size_t)src * MAXS + slot] = (unsigned)dst | ((unsigned)re << 16);
  }
}

// ---- per-edge R (1 wave/atom, 2 slots/lane) + per-atom softmax m,s --------
__global__ __launch_bounds__(256) void k_edgeR(
    const int* __restrict__ cnt_src, const unsigned* __restrict__ pay,
    const float* __restrict__ coords, const float* __restrict__ Qa,
    const float* __restrict__ Ka, const float* __restrict__ rlb,
    const f32x4* __restrict__ tab, float* __restrict__ R_slab,
    f32x4* __restrict__ msm, f32x4* __restrict__ mss) {
  int l = threadIdx.x & 63;
  int a = blockIdx.x * 4 + (threadIdx.x >> 6);
  int n = cnt_src[a];
  if (n > MAXS) n = MAXS;
  size_t base = (size_t)a * MAXS;
  float ax = coords[a * 3 + 0], ay = coords[a * 3 + 1], az = coords[a * 3 + 2];
  const float4* qp = (const float4*)(Qa + (size_t)a * 64);
  bool a0 = l < n, a1 = l + 64 < n;
  f32x4 R0, R1;
#pragma unroll
  for (int sl = 0; sl < 2; ++sl) {
    bool act = sl ? a1 : a0;
    f32x4 Rv = {-3.0e38f, -3.0e38f, -3.0e38f, -3.0e38f};
    if (act) {
      int s = l + sl * 64;
      unsigned pr = pay[base + s];
      int dst = (int)(pr & 0xFFFFu);
      int re = (int)(pr >> 16);
      float vx = coords[dst * 3 + 0] - ax + 1e-8f;
      float vy = coords[dst * 3 + 1] - ay + 1e-8f;
      float vz = coords[dst * 3 + 2] - az + 1e-8f;
      float d = sqrtf(vx * vx + vy * vy + vz * vz);
      float x = d * TINV;
      int i = (int)x;
      if (i > TABN - 2) i = TABN - 2;
      float fr = x - (float)i;
      f32x4 t0 = tab[i], t1 = tab[i + 1];
      f32x4 adb = t0 + (t1 - t0) * fr;
      const float4* kp = (const float4*)(Ka + (size_t)dst * 64);
      float4 rlb4 = *(const float4*)(rlb + re * 4);
      const float* rlbp = (const float*)&rlb4;
#pragma unroll
      for (int h = 0; h < NH; ++h) {
        float dot = 0.f;
#pragma unroll
        for (int v4 = 0; v4 < 4; ++v4) {
          float4 q4 = qp[h * 4 + v4];
          float4 k4 = kp[h * 4 + v4];
          dot += q4.x * k4.x + q4.y * k4.y + q4.z * k4.z + q4.w * k4.w;
        }
        Rv[h] = dot * 0.25f + rlbp[h] + adb[h];
      }
      __builtin_nontemporal_store(Rv, (f32x4*)(R_slab + (base + s) * 4));
    }
    if (sl) R1 = Rv; else R0 = Rv;
  }
  f32x4 mx;
#pragma unroll
  for (int h = 0; h < NH; ++h) mx[h] = fmaxf(R0[h], R1[h]);
#pragma unroll
  for (int off = 1; off < 64; off <<= 1) {
#pragma unroll
    for (int h = 0; h < NH; ++h) mx[h] = fmaxf(mx[h], __shfl_xor(mx[h], off));
  }
  f32x4 ex;
#pragma unroll
  for (int h = 0; h < NH; ++h)
    ex[h] = (a0 ? __expf(R0[h] - mx[h]) : 0.f) +
            (a1 ? __expf(R1[h] - mx[h]) : 0.f);
#pragma unroll
  for (int off = 1; off < 64; off <<= 1) {
#pragma unroll
    for (int h = 0; h < NH; ++h) ex[h] += __shfl_xor(ex[h], off);
  }
  if (l == 0) {
    msm[a] = mx;
    mss[a] = ex;
  }
}

// ---- per-re counts+sums in ONE slab pass (LDS-replicated), 256 blocks -----
__global__ __launch_bounds__(1024) void k_re2(
    const int* __restrict__ cnt_src, const unsigned* __restrict__ pay,
    const float* __restrict__ R_slab, unsigned short* __restrict__ cntg16,
    float* __restrict__ br_g) {
  __shared__ unsigned scntP[E_RES / 2];  // 8KB packed u16
  __shared__ float sbr[E_RES * 4];       // 64KB
  int tid = threadIdx.x;
  int bid = blockIdx.x;
  int wv = tid >> 6, lane = tid & 63;
  int gw = bid * 16 + wv;
  for (int j = tid; j < E_RES / 2; j += 1024) scntP[j] = 0u;
  for (int j = tid; j < E_RES * 4; j += 1024) sbr[j] = 0.f;
  __syncthreads();
  for (int a = gw; a < N_ATOM; a += NBRE * 16) {
    int n = cnt_src[a];
    if (n > MAXS) n = MAXS;
    size_t base = (size_t)a * MAXS;
    for (int i = lane; i < n; i += 64) {
      int re = (int)(pay[base + i] >> 16);
      atomicAdd(&scntP[re >> 1], (re & 1) ? 65536u : 1u);
      f32x4 r = *(const f32x4*)(R_slab + (base + i) * 4);
      atomicAdd(&sbr[re * 4 + 0], r[0]);
      atomicAdd(&sbr[re * 4 + 1], r[1]);
      atomicAdd(&sbr[re * 4 + 2], r[2]);
      atomicAdd(&sbr[re * 4 + 3], r[3]);
    }
  }
  __syncthreads();
  for (int j = tid; j < E_RES; j += 1024) {
    unsigned v = scntP[j >> 1];
    cntg16[(size_t)bid * E_RES + j] =
        (unsigned short)((j & 1) ? (v >> 16) : (v & 0xFFFFu));
  }
  for (int j = tid; j < E_RES * 4; j += 1024)
    br_g[(size_t)bid * E_RES * 4 + j] = sbr[j];
}

// ---- reduce the 256 copies -> block_r (already divided by count) ----------
__global__ __launch_bounds__(256) void k_red(
    const float* __restrict__ br_g, const unsigned short* __restrict__ cntg16,
    float* __restrict__ block_r) {
  int t = blockIdx.x * blockDim.x + threadIdx.x;
  if (t >= E_RES * 4) return;
  int r = t >> 2;
  float s = 0.f;
  int c = 0;
  for (int b = 0; b < NBRE; ++b) {
    s += br_g[(size_t)b * E_RES * 4 + t];
    c += (int)cntg16[(size_t)b * E_RES + r];
  }
  block_r[t] = s / fmaxf((float)c, 1.0f);
}

// ---- residue softmax (max, denom, beta) fully in LDS, single block --------
__global__ __launch_bounds__(1024) void k_br23(
    const float* __restrict__ block_r, const int* __restrict__ rei,
    float* __restrict__ beta) {
  __shared__ unsigned resm[N_RES * 4];
  __shared__ float ress[N_RES * 4];
  int tid = threadIdx.x;
  for (int j = tid; j < N_RES * 4; j += 1024) { resm[j] = 0u; ress[j] = 0.f; }
  __syncthreads();
  float brv[4][4];
  int r1v[4];
  for (int k = 0; k < 4; ++k) {
    int r = tid + k * 1024;
    if (r < E_RES) {
      r1v[k] = rei[E_RES + r];
#pragma unroll
      for (int h = 0; h < 4; ++h) {
        brv[k][h] = block_r[r * 4 + h];
        atomicMax(&resm[r1v[k] * 4 + h], enc_f(brv[k][h]));
      }
    }
  }
  __syncthreads();
  for (int k = 0; k < 4; ++k) {
    int r = tid + k * 1024;
    if (r < E_RES) {
#pragma unroll
      for (int h = 0; h < 4; ++h)
        atomicAdd(&ress[r1v[k] * 4 + h],
                  __expf(brv[k][h] - dec_f(resm[r1v[k] * 4 + h])));
    }
  }
  __syncthreads();
  for (int k = 0; k < 4; ++k) {
    int r = tid + k * 1024;
    if (r < E_RES) {
#pragma unroll
      for (int h = 0; h < 4; ++h)
        beta[r * 4 + h] = __expf(brv[k][h] - dec_f(resm[r1v[k] * 4 + h])) /
                          (ress[r1v[k] * 4 + h] + 1e-16f);
    }
  }
}

// ---- per src atom: single-pass weighted V + fused output GEMM -------------
__global__ __launch_bounds__(256) void k_src(
    const int* __restrict__ cnt_src, const unsigned* __restrict__ pay,
    const float* __restrict__ R_slab, const float* __restrict__ beta,
    const float* __restrict__ Va, const f32x4* __restrict__ msm,
    const f32x4* __restrict__ mss, const float* __restrict__ wo,
    const float* __restrict__ bo, float* __restrict__ out) {
  __shared__ float sau[4][64];
  int wv = threadIdx.x >> 6, l = threadIdx.x & 63;
  int wid = blockIdx.x * 4 + wv;
  int n = cnt_src[wid];
  if (n > MAXS) n = MAXS;
  int h = l >> 4;
  size_t rbase = (size_t)wid * MAXS;
  f32x4 m4 = msm[wid], s4 = mss[wid];
  float mh = m4[h];
  float sden = s4[h] + 1e-16f;
  float acc = 0.f;
#pragma unroll 4
  for (int i = 0; i < n; ++i) {
    unsigned pr = pay[rbase + i];
    int dst = (int)(pr & 0xFFFFu);
    int re = (int)(pr >> 16);
    float rv = R_slab[(rbase + i) * 4 + h];
    float bt = beta[re * 4 + h];
    float v = Va[(size_t)dst * 64 + l];
    acc += __expf(rv - mh) * bt * v;
  }
  sau[wv][l] = acc / sden;
  __syncthreads();
  int p = l >> 4, c = l & 15;
  float part = 0.f;
#pragma unroll
  for (int jj = 0; jj < 16; ++jj)
    part += sau[wv][p * 16 + jj] * wo[(p * 16 + jj) * 16 + c];
  part += __shfl_down(part, 32);
  part += __shfl_down(part, 16);
  if (l < 16) out[wid * 16 + c] = part + bo[c];
}

extern "C" void kernel_launch(void* const* d_in, const int* in_sizes, int n_in,
                              void* d_out, int out_size, void* d_ws,
                              size_t ws_size, hipStream_t stream) {
  const float* nf   = (const float*)d_in[0];
  const float* ref_ = (const float*)d_in[1];
  const int*   rei  = (const int*)d_in[2];
  const float* af   = (const float*)d_in[3];
  const float* co   = (const float*)d_in[4];
  const int*   cei  = (const int*)d_in[5];
  const int*   aer  = (const int*)d_in[6];
  const float* rw1  = (const float*)d_in[7];
  const float* rb1  = (const float*)d_in[8];
  const float* rw2  = (const float*)d_in[9];
  const float* rb2  = (const float*)d_in[10];
  const float* rw3  = (const float*)d_in[11];
  const float* rb3  = (const float*)d_in[12];
  const float* w1   = (const float*)d_in[13];
  const float* b1   = (const float*)d_in[14];
  const float* w2   = (const float*)d_in[15];
  const float* b2   = (const float*)d_in[16];
  const float* wq   = (const float*)d_in[17];
  const float* bq   = (const float*)d_in[18];
  const float* wkv  = (const float*)d_in[19];
  const float* bkv  = (const float*)d_in[20];
  const float* wo   = (const float*)d_in[21];
  const float* bo   = (const float*)d_in[22];
  float* out = (float*)d_out;

  float* ws = (float*)d_ws;
  float*    Qa      = ws;                            //  896000
  float*    Ka      = Qa + 896000;                   //  896000
  float*    Va      = Ka + 896000;                   //  896000
  float*    rlb     = Va + 896000;                   //   16000
  float*    R_slab  = rlb + 16000;                   // 7168000
  unsigned* pay     = (unsigned*)(R_slab + 7168000); // 1792000
  float*    br_g    = (float*)(pay + 1792000);       // 4096000 (256*16000)
  unsigned short* cntg16 = (unsigned short*)(br_g + 4096000);  // 1024000 u16
  int*      cnt_src = (int*)(cntg16 + 1024000);      //   14000
  float*    block_r = (float*)(cnt_src + 14000);     //   16000
  f32x4*    tab     = (f32x4*)(block_r + 16000);     //   65540 floats
  f32x4*    msm     = (f32x4*)((float*)tab + 65544); //   56000 floats
  f32x4*    mss     = (f32x4*)((float*)msm + 56000); //   56000 floats
  // overlays:
  unsigned* ghistP  = (unsigned*)br_g;   // 256*7000 u32, dead before k_re2
  unsigned short* ofs16 = (unsigned short*)R_slab;  // 256*14000 u16, dead before k_edgeR
  float*    beta    = Ka + 16000;        // dead region of Ka after k_edgeR

  k_hist<<<NHB, 256, 0, stream>>>(cei, ghistP);
  kA2<<<PROJ_BLKS + RLB_BLKS + TAB_BLKS, 256, 0, stream>>>(
      af, wq, bq, wkv, bkv, Qa, Ka, Va, ref_, nf, rei, w1, b1, w2, b2, rlb,
      rw1, rb1, rw2, rb2, rw3, rb3, tab);
  k_ofs<<<(N_ATOM + 255) / 256, 256, 0, stream>>>(ghistP, ofs16, cnt_src);
  k_scat<<<NHB, 256, 0, stream>>>(cei, aer, (const unsigned*)ofs16, pay);
  k_edgeR<<<N_ATOM / 4, 256, 0, stream>>>(cnt_src, pay, co, Qa, Ka, rlb, tab,
                                          R_slab, msm, mss);
  k_re2<<<NBRE, 1024, 0, stream>>>(cnt_src, pay, R_slab, cntg16, br_g);
  k_red<<<(E_RES * 4 + 255) / 256, 256, 0, stream>>>(br_g, cntg16, block_r);
  k_br23<<<1, 1024, 0, stream>>>(block_r, rei, beta);
  k_src<<<N_ATOM / 4, 256, 0, stream>>>(cnt_src, pay, R_slab, beta, Va, msm,
                                        mss, wo, bo, out);
}